// Round 14
// baseline (509.322 us; speedup 1.0000x reference)
//
#include <hip/hip_runtime.h>
#include <cstdio>

typedef unsigned short u16;
typedef u16 u16x8 __attribute__((ext_vector_type(8)));
typedef __bf16 bf16x8 __attribute__((ext_vector_type(8)));
typedef float f32x4 __attribute__((ext_vector_type(4)));

#define AS1 __attribute__((address_space(1)))
#define AS3 __attribute__((address_space(3)))

#define GLOAD16(gsrc, ldst) __builtin_amdgcn_global_load_lds( \
    (const AS1 void*)(gsrc), (AS3 void*)(ldst), 16, 0, 0)

__device__ __forceinline__ u16 f2bf(float f) {
  unsigned u = __builtin_bit_cast(unsigned, f);
  u += 0x7fffu + ((u >> 16) & 1u);
  return (u16)(u >> 16);
}
__device__ __forceinline__ float bf2f(u16 h) {
  return __builtin_bit_cast(float, (unsigned)h << 16);
}

// ---------------- fp32 -> bf16 convert (with trailing-row zero pad) ----------
__global__ __launch_bounds__(256) void cvt_pad_k(const float* __restrict__ src,
                                                 u16* __restrict__ dst,
                                                 long srcN, long dstN) {
  long i = ((long)blockIdx.x * 256 + threadIdx.x) * 8;
  const long stride = (long)gridDim.x * 256 * 8;
  for (; i < dstN; i += stride) {
    u16x8 o = {0,0,0,0,0,0,0,0};
    if (i < srcN) {
      const float4* p = (const float4*)(src + i);
      float4 a = p[0], b = p[1];
      o[0]=f2bf(a.x); o[1]=f2bf(a.y); o[2]=f2bf(a.z); o[3]=f2bf(a.w);
      o[4]=f2bf(b.x); o[5]=f2bf(b.y); o[6]=f2bf(b.z); o[7]=f2bf(b.w);
    }
    *(u16x8*)(dst + i) = o;
  }
}

// ---------------- RMSNorm over last dim (bf16 in/out, fp32 math) -------------
__global__ __launch_bounds__(256) void rms_k(const u16* __restrict__ src, u16* __restrict__ dst,
                                             const float* __restrict__ w,
                                             int sstride, int dstride, int cols) {
  const int row = blockIdx.x;
  const int tid = threadIdx.x;
  const int nch = cols >> 3;
  float x[8];
  float ss = 0.f;
  if (tid < nch) {
    u16x8 v = *(const u16x8*)(src + (size_t)row * sstride + tid * 8);
#pragma unroll
    for (int j = 0; j < 8; ++j) { x[j] = bf2f(v[j]); ss += x[j] * x[j]; }
  } else {
#pragma unroll
    for (int j = 0; j < 8; ++j) x[j] = 0.f;
  }
#pragma unroll
  for (int off = 1; off < 64; off <<= 1) ss += __shfl_xor(ss, off);
  __shared__ float red[4];
  const int wv = tid >> 6, ln = tid & 63;
  if (ln == 0) red[wv] = ss;
  __syncthreads();
  const float tot = red[0] + red[1] + red[2] + red[3];
  const float rs = 1.0f / sqrtf(tot / (float)cols + 1e-6f);
  if (tid < nch) {
    u16x8 o;
#pragma unroll
    for (int j = 0; j < 8; ++j) o[j] = f2bf(x[j] * rs * w[tid * 8 + j]);
    *(u16x8*)(dst + (size_t)row * dstride + tid * 8) = o;
  }
}

// ---------------- RoPE: q_pe (in place, 16 heads) + k_pe -> kpe --------------
__global__ __launch_bounds__(256) void rope_k(u16* __restrict__ q, const u16* __restrict__ kva,
                                              u16* __restrict__ kpe, const int* __restrict__ pos) {
  const int tok = blockIdx.x;          // 0..4095
  const int j = threadIdx.x & 63;
  const int w = threadIdx.x >> 6;
  const float p = (float)pos[tok];
  const int jj = j & 31;
  const float inv = __powf(10000.0f, -(float)jj * (1.0f / 32.0f));
  float s, c;
  __sincosf(p * inv, &s, &c);
  const float sgn = (j < 32) ? -1.0f : 1.0f;
  const int partner = (j < 32) ? j + 32 : j - 32;
  if (w == 0) {
    const float x  = bf2f(kva[(size_t)tok * 640 + 512 + j]);
    const float xp = bf2f(kva[(size_t)tok * 640 + 512 + partner]);
    kpe[(size_t)tok * 64 + j] = f2bf(x * c + sgn * xp * s);
  }
#pragma unroll
  for (int hh = 0; hh < 4; ++hh) {
    const int h = w * 4 + hh;
    const size_t base = (size_t)tok * 3072 + h * 192 + 128;
    const float x  = bf2f(q[base + j]);
    const float xp = bf2f(q[base + partner]);
    q[base + j] = f2bf(x * c + sgn * xp * s);
  }
}

// ---------------- bf16 GEMM: C[M,N] = A[M,K] * B[N,K]^T ----------------------
__global__ __launch_bounds__(256) void gemm_bt(const u16* __restrict__ A, const u16* __restrict__ B,
                                               u16* __restrict__ Cb, float* __restrict__ Cf,
                                               int M, int N, int K) {
  __shared__ __attribute__((aligned(16))) u16 As[128 * 64];
  __shared__ __attribute__((aligned(16))) u16 Bs[128 * 64];
  const int tid = threadIdx.x;
  const int m0 = blockIdx.y * 128, n0 = blockIdx.x * 128;
  const int w = tid >> 6, lane = tid & 63;
  const int wr = w >> 1, wc = w & 1;
  const int lr = lane & 15, g = lane >> 4;

  f32x4 acc[4][4] = {};

  for (int k0 = 0; k0 < K; k0 += 64) {
#pragma unroll
    for (int i = 0; i < 4; ++i) {
      const int c = i * 256 + tid;
      const int row = c >> 3, col = (c & 7) << 3;
      GLOAD16(A + (size_t)(m0 + row) * K + k0 + col, &As[c * 8]);
    }
#pragma unroll
    for (int i = 0; i < 4; ++i) {
      const int c = i * 256 + tid;
      const int row = c >> 3, col = (c & 7) << 3;
      GLOAD16(B + (size_t)(n0 + row) * K + k0 + col, &Bs[c * 8]);
    }
    __syncthreads();
    bf16x8 af[4][2], bfr[4][2];
#pragma unroll
    for (int x = 0; x < 4; ++x)
#pragma unroll
      for (int kk = 0; kk < 2; ++kk) {
        af[x][kk]  = *(const bf16x8*)(&As[(wr * 64 + x * 16 + lr) * 64 + kk * 32 + g * 8]);
        bfr[x][kk] = *(const bf16x8*)(&Bs[(wc * 64 + x * 16 + lr) * 64 + kk * 32 + g * 8]);
      }
#pragma unroll
    for (int mi = 0; mi < 4; ++mi)
#pragma unroll
      for (int ni = 0; ni < 4; ++ni)
#pragma unroll
        for (int kk = 0; kk < 2; ++kk)
          acc[mi][ni] = __builtin_amdgcn_mfma_f32_16x16x32_bf16(af[mi][kk], bfr[ni][kk],
                                                                acc[mi][ni], 0, 0, 0);
    __syncthreads();
  }

  const int rb = m0 + wr * 64, cb = n0 + wc * 64;
#pragma unroll
  for (int mi = 0; mi < 4; ++mi)
#pragma unroll
    for (int ni = 0; ni < 4; ++ni)
#pragma unroll
      for (int i = 0; i < 4; ++i) {
        const int r = rb + mi * 16 + g * 4 + i;
        const int cI = cb + ni * 16 + lr;
        if (Cf) Cf[(size_t)r * N + cI] = acc[mi][ni][i];
        else    Cb[(size_t)r * N + cI] = f2bf(acc[mi][ni][i]);
      }
}

// ---------------- V transpose: kvb V-half -> vT[bh*128+v][seq] ---------------
__global__ __launch_bounds__(256) void vtr_k(const u16* __restrict__ kvb, u16* __restrict__ vT) {
  __shared__ u16 tile[128 * 72];             // [v][s], stride 72 keeps b128 align
  const int bh = blockIdx.x, b = bh >> 4, h = bh & 15;
  const int s0 = blockIdx.y * 64;
  const int t = threadIdx.x;
  {
    const int s = t >> 2;                    // 0..63
    const int vc = (t & 3) * 32;             // 0,32,64,96
    const u16* src = kvb + (size_t)(b * 2048 + s0 + s) * 4096 + h * 256 + 128 + vc;
#pragma unroll
    for (int c = 0; c < 4; ++c) {
      u16x8 v = *(const u16x8*)(src + c * 8);
#pragma unroll
      for (int e = 0; e < 8; ++e) tile[(vc + c * 8 + e) * 72 + s] = v[e];
    }
  }
  __syncthreads();
  {
    const int v = t >> 1;                    // 0..127
    const int sh = (t & 1) * 32;
    u16* dst = vT + (size_t)(bh * 128 + v) * 2048 + s0 + sh;
    const u16* srow = &tile[v * 72 + sh];
#pragma unroll
    for (int c = 0; c < 4; ++c)
      *(u16x8*)(dst + c * 8) = *(const u16x8*)(srow + c * 8);
  }
}

// ---------------- causal flash attention, per (b,head) -----------------------
// r13 template; ONLY change: balanced complementary pairing. Co-resident block
// pairs (bid, bid+256) get q-tiles (15-by, by) -> every CU totals 34 tile-units
// (was 48..18 with heavy-first alone).
__global__ __launch_bounds__(256) void attn_k(const u16* __restrict__ q, const u16* __restrict__ kvb,
                                              const u16* __restrict__ kpe, const u16* __restrict__ vT,
                                              u16* __restrict__ ao) {
  __shared__ __attribute__((aligned(16))) u16 Ks[64 * 192];   // also holds Ps after QK
  __shared__ __attribute__((aligned(16))) u16 Vt[128 * 64];   // [v][k-chunk swizzled]

  const float SCALE = 0.07216878364870323f;  // 192^-0.5
  const int bh = blockIdx.x;
  const int b = bh >> 4, h = bh & 15;
  const int by = blockIdx.y;
  const int j = (by < 8) ? (15 - by) : (by - 8);   // pair sums = 15 (balanced)
  const int tid = threadIdx.x, w = tid >> 6, lane = tid & 63;
  const int lr = lane & 15, g = lane >> 4;

  const int q0 = j * 128;
  const int qrb = q0 + w * 32;
  u16* Psw = &Ks[w * 2304];                  // per-wave 32x72 slice inside Ks

  bf16x8 qf[2][6];
#pragma unroll
  for (int m = 0; m < 2; ++m)
#pragma unroll
    for (int kd = 0; kd < 6; ++kd)
      qf[m][kd] = *(const bf16x8*)(q + (size_t)(b * 2048 + qrb + m * 16 + lr) * 3072 +
                                   h * 192 + kd * 32 + g * 8);

  float mrow[2][4], lrow[2][4];
  f32x4 o[2][8] = {};
#pragma unroll
  for (int m = 0; m < 2; ++m)
#pragma unroll
    for (int i = 0; i < 4; ++i) { mrow[m][i] = -1e30f; lrow[m][i] = 0.f; }

  const int nt = (q0 >> 6) + 2;
  for (int t = 0; t < nt; ++t) {
    const int k0 = t * 64;
    // stage K tile (64 x 192), swizzled source -> linear LDS
#pragma unroll
    for (int i = 0; i < 6; ++i) {
      const int c = i * 256 + tid;           // 0..1535
      const int row = c / 24, cl = c - row * 24;
      const int cg = cl ^ (row & 7);
      const u16* src = (cg < 16)
        ? (kvb + (size_t)(b * 2048 + k0 + row) * 4096 + h * 256 + cg * 8)
        : (kpe + (size_t)(b * 2048 + k0 + row) * 64 + (cg - 16) * 8);
      GLOAD16(src, &Ks[c * 8]);
    }
    // stage V^T tile (128 v x 64 k) from vT: linear LDS, swizzled source chunk
#pragma unroll
    for (int i = 0; i < 4; ++i) {
      const int c = i * 256 + tid;           // 0..1023
      const int v = c >> 3, cl = c & 7;
      const int cg = cl ^ (v & 7);
      GLOAD16(vT + (size_t)(bh * 128 + v) * 2048 + k0 + cg * 8, &Vt[c * 8]);
    }
    __syncthreads();

    const bool active = (k0 <= qrb + 31);    // wave-uniform
    f32x4 sAcc[2][4] = {};
    if (active) {
      // S = Q K^T (32 rows x 64 keys per wave)
#pragma unroll
      for (int nf = 0; nf < 4; ++nf) {
        const int rr = nf * 16 + lr;
#pragma unroll
        for (int kd = 0; kd < 6; ++kd) {
          const int ch = (kd * 4 + g) ^ (rr & 7);
          const bf16x8 kf = *(const bf16x8*)(&Ks[rr * 192 + ch * 8]);
#pragma unroll
          for (int m = 0; m < 2; ++m)
            sAcc[m][nf] = __builtin_amdgcn_mfma_f32_16x16x32_bf16(qf[m][kd], kf, sAcc[m][nf], 0, 0, 0);
        }
      }
    }
    __syncthreads();                         // all Ks reads done; Ps may overwrite

    if (active) {
      // online softmax over 64 keys
#pragma unroll
      for (int m = 0; m < 2; ++m) {
        float sv[4][4];
#pragma unroll
        for (int nf = 0; nf < 4; ++nf)
#pragma unroll
          for (int i = 0; i < 4; ++i) {
            const int qrow = qrb + m * 16 + g * 4 + i;
            const int kcol = k0 + nf * 16 + lr;
            const float vS = sAcc[m][nf][i] * SCALE;
            sv[nf][i] = (kcol > qrow) ? -1e30f : vS;
          }
        float fac[4], mn[4];
#pragma unroll
        for (int i = 0; i < 4; ++i) {
          float rm = fmaxf(fmaxf(sv[0][i], sv[1][i]), fmaxf(sv[2][i], sv[3][i]));
          rm = fmaxf(rm, __shfl_xor(rm, 1));
          rm = fmaxf(rm, __shfl_xor(rm, 2));
          rm = fmaxf(rm, __shfl_xor(rm, 4));
          rm = fmaxf(rm, __shfl_xor(rm, 8));
          mn[i] = fmaxf(mrow[m][i], rm);
          fac[i] = __expf(mrow[m][i] - mn[i]);
          mrow[m][i] = mn[i];
        }
#pragma unroll
        for (int i = 0; i < 4; ++i) {
          float rsum = 0.f;
#pragma unroll
          for (int nf = 0; nf < 4; ++nf) { sv[nf][i] = __expf(sv[nf][i] - mn[i]); rsum += sv[nf][i]; }
          rsum += __shfl_xor(rsum, 1);
          rsum += __shfl_xor(rsum, 2);
          rsum += __shfl_xor(rsum, 4);
          rsum += __shfl_xor(rsum, 8);
          lrow[m][i] = lrow[m][i] * fac[i] + rsum;
        }
#pragma unroll
        for (int nv = 0; nv < 8; ++nv)
#pragma unroll
          for (int i = 0; i < 4; ++i) o[m][nv][i] *= fac[i];
#pragma unroll
        for (int nf = 0; nf < 4; ++nf)
#pragma unroll
          for (int i = 0; i < 4; ++i)
            Psw[(m * 16 + g * 4 + i) * 72 + nf * 16 + lr] = f2bf(sv[nf][i]);
      }
      asm volatile("s_waitcnt lgkmcnt(0)" ::: "memory");

      // O += P V  (two K=32 sub-steps)
#pragma unroll
      for (int kc = 0; kc < 2; ++kc) {
        bf16x8 vfr[8];
#pragma unroll
        for (int nv = 0; nv < 8; ++nv) {
          const int v = nv * 16 + lr;
          const int cx = (kc * 4 + g) ^ (v & 7);
          vfr[nv] = *(const bf16x8*)(&Vt[v * 64 + cx * 8]);
        }
#pragma unroll
        for (int m = 0; m < 2; ++m) {
          const bf16x8 pf = *(const bf16x8*)(&Psw[(m * 16 + lr) * 72 + kc * 32 + g * 8]);
#pragma unroll
          for (int nv = 0; nv < 8; ++nv)
            o[m][nv] = __builtin_amdgcn_mfma_f32_16x16x32_bf16(pf, vfr[nv], o[m][nv], 0, 0, 0);
        }
      }
    }
    __syncthreads();                         // Ps/Vt reads done before next stage
  }

  // epilogue: normalize and store
#pragma unroll
  for (int m = 0; m < 2; ++m)
#pragma unroll
    for (int i = 0; i < 4; ++i) {
      const float inv = 1.0f / lrow[m][i];
      const size_t tokOff = (size_t)(b * 2048 + qrb + m * 16 + g * 4 + i) * 2048 + h * 128;
#pragma unroll
      for (int nv = 0; nv < 8; ++nv)
        ao[tokOff + nv * 16 + lr] = f2bf(o[m][nv][i] * inv);
    }
}

// -----------------------------------------------------------------------------
extern "C" void kernel_launch(void* const* d_in, const int* in_sizes, int n_in,
                              void* d_out, int out_size, void* d_ws, size_t ws_size,
                              hipStream_t stream) {
  const float* hidden  = (const float*)d_in[0];
  const int*   pos     = (const int*)d_in[1];
  const float* q_a_w   = (const float*)d_in[2];
  const float* q_a_ln  = (const float*)d_in[3];
  const float* q_b_w   = (const float*)d_in[4];
  const float* kv_a_w  = (const float*)d_in[5];
  const float* kv_a_ln = (const float*)d_in[6];
  const float* kv_b_w  = (const float*)d_in[7];
  const float* o_w     = (const float*)d_in[8];
  float* out = (float*)d_out;

  char* ws = (char*)d_ws;
  u16* hb  = (u16*)(ws + 0L);          // 4096x2048 (reused as vT after kv_a gemm)
  u16* w1  = (u16*)(ws + 16777216L);   // 1536x2048
  u16* w2  = (u16*)(ws + 23068672L);   // 3072x1536
  u16* w3  = (u16*)(ws + 32505856L);   // 640x2048 (padded)
  u16* w4  = (u16*)(ws + 35127296L);   // 4096x512
  u16* w5  = (u16*)(ws + 39321600L);   // 2048x2048
  u16* qa  = (u16*)(ws + 47710208L);   // 4096x1536
  u16* qb  = (u16*)(ws + 60293120L);   // 4096x3072
  u16* kva = (u16*)(ws + 85458944L);   // 4096x640
  u16* ckv = (u16*)(ws + 90701824L);   // 4096x512
  u16* kpe = (u16*)(ws + 94896128L);   // 4096x64
  u16* kvb = (u16*)(ws + 95420416L);   // 4096x4096
  u16* ao  = (u16*)(ws + 128974848L);  // 4096x2048
  u16* vT  = hb;                       // 4096x2048, hb dead after kv_a gemm
  if (ws_size < 145752064UL) { fprintf(stderr, "ws too small: %zu\n", ws_size); return; }

  auto cvt = [&](const float* s, u16* d, long sn, long dn) {
    long blocks = (dn / 8 + 255) / 256; if (blocks > 2048) blocks = 2048;
    cvt_pad_k<<<dim3((unsigned)blocks), dim3(256), 0, stream>>>(s, d, sn, dn);
  };
  cvt(hidden, hb, 4096L * 2048, 4096L * 2048);
  cvt(q_a_w,  w1, 1536L * 2048, 1536L * 2048);
  cvt(q_b_w,  w2, 3072L * 1536, 3072L * 1536);
  cvt(kv_a_w, w3, 576L * 2048,  640L * 2048);
  cvt(kv_b_w, w4, 4096L * 512,  4096L * 512);
  cvt(o_w,    w5, 2048L * 2048, 2048L * 2048);

  gemm_bt<<<dim3(12, 32), 256, 0, stream>>>(hb, w1, qa, nullptr, 4096, 1536, 2048);
  rms_k<<<4096, 256, 0, stream>>>(qa, qa, q_a_ln, 1536, 1536, 1536);
  gemm_bt<<<dim3(24, 32), 256, 0, stream>>>(qa, w2, qb, nullptr, 4096, 3072, 1536);
  gemm_bt<<<dim3(5, 32), 256, 0, stream>>>(hb, w3, kva, nullptr, 4096, 640, 2048);
  rms_k<<<4096, 256, 0, stream>>>(kva, ckv, kv_a_ln, 640, 512, 512);
  rope_k<<<4096, 256, 0, stream>>>(qb, kva, kpe, pos);
  gemm_bt<<<dim3(32, 32), 256, 0, stream>>>(ckv, w4, kvb, nullptr, 4096, 4096, 512);
  vtr_k<<<dim3(32, 32), 256, 0, stream>>>(kvb, vT);
  attn_k<<<dim3(32, 16), 256, 0, stream>>>(qb, kvb, kpe, vT, ao);
  gemm_bt<<<dim3(16, 32), 256, 0, stream>>>(ao, w5, nullptr, out, 4096, 2048, 2048);
}

// Round 15
// 471.921 us; speedup vs baseline: 1.0793x; 1.0793x over previous
//
#include <hip/hip_runtime.h>
#include <cstdio>

typedef unsigned short u16;
typedef u16 u16x8 __attribute__((ext_vector_type(8)));
typedef __bf16 bf16x8 __attribute__((ext_vector_type(8)));
typedef float f32x4 __attribute__((ext_vector_type(4)));

#define AS1 __attribute__((address_space(1)))
#define AS3 __attribute__((address_space(3)))

#define GLOAD16(gsrc, ldst) __builtin_amdgcn_global_load_lds( \
    (const AS1 void*)(gsrc), (AS3 void*)(ldst), 16, 0, 0)

__device__ __forceinline__ u16 f2bf(float f) {
  unsigned u = __builtin_bit_cast(unsigned, f);
  u += 0x7fffu + ((u >> 16) & 1u);
  return (u16)(u >> 16);
}
__device__ __forceinline__ float bf2f(u16 h) {
  return __builtin_bit_cast(float, (unsigned)h << 16);
}

// ---------------- fp32 -> bf16 convert (with trailing-row zero pad) ----------
__global__ __launch_bounds__(256) void cvt_pad_k(const float* __restrict__ src,
                                                 u16* __restrict__ dst,
                                                 long srcN, long dstN) {
  long i = ((long)blockIdx.x * 256 + threadIdx.x) * 8;
  const long stride = (long)gridDim.x * 256 * 8;
  for (; i < dstN; i += stride) {
    u16x8 o = {0,0,0,0,0,0,0,0};
    if (i < srcN) {
      const float4* p = (const float4*)(src + i);
      float4 a = p[0], b = p[1];
      o[0]=f2bf(a.x); o[1]=f2bf(a.y); o[2]=f2bf(a.z); o[3]=f2bf(a.w);
      o[4]=f2bf(b.x); o[5]=f2bf(b.y); o[6]=f2bf(b.z); o[7]=f2bf(b.w);
    }
    *(u16x8*)(dst + i) = o;
  }
}

// ---------------- RMSNorm over last dim (bf16 in/out, fp32 math) -------------
__global__ __launch_bounds__(256) void rms_k(const u16* __restrict__ src, u16* __restrict__ dst,
                                             const float* __restrict__ w,
                                             int sstride, int dstride, int cols) {
  const int row = blockIdx.x;
  const int tid = threadIdx.x;
  const int nch = cols >> 3;
  float x[8];
  float ss = 0.f;
  if (tid < nch) {
    u16x8 v = *(const u16x8*)(src + (size_t)row * sstride + tid * 8);
#pragma unroll
    for (int j = 0; j < 8; ++j) { x[j] = bf2f(v[j]); ss += x[j] * x[j]; }
  } else {
#pragma unroll
    for (int j = 0; j < 8; ++j) x[j] = 0.f;
  }
#pragma unroll
  for (int off = 1; off < 64; off <<= 1) ss += __shfl_xor(ss, off);
  __shared__ float red[4];
  const int wv = tid >> 6, ln = tid & 63;
  if (ln == 0) red[wv] = ss;
  __syncthreads();
  const float tot = red[0] + red[1] + red[2] + red[3];
  const float rs = 1.0f / sqrtf(tot / (float)cols + 1e-6f);
  if (tid < nch) {
    u16x8 o;
#pragma unroll
    for (int j = 0; j < 8; ++j) o[j] = f2bf(x[j] * rs * w[tid * 8 + j]);
    *(u16x8*)(dst + (size_t)row * dstride + tid * 8) = o;
  }
}

// ---------------- RoPE: q_pe (in place, 16 heads) + k_pe -> kpe --------------
__global__ __launch_bounds__(256) void rope_k(u16* __restrict__ q, const u16* __restrict__ kva,
                                              u16* __restrict__ kpe, const int* __restrict__ pos) {
  const int tok = blockIdx.x;          // 0..4095
  const int j = threadIdx.x & 63;
  const int w = threadIdx.x >> 6;
  const float p = (float)pos[tok];
  const int jj = j & 31;
  const float inv = __powf(10000.0f, -(float)jj * (1.0f / 32.0f));
  float s, c;
  __sincosf(p * inv, &s, &c);
  const float sgn = (j < 32) ? -1.0f : 1.0f;
  const int partner = (j < 32) ? j + 32 : j - 32;
  if (w == 0) {
    const float x  = bf2f(kva[(size_t)tok * 640 + 512 + j]);
    const float xp = bf2f(kva[(size_t)tok * 640 + 512 + partner]);
    kpe[(size_t)tok * 64 + j] = f2bf(x * c + sgn * xp * s);
  }
#pragma unroll
  for (int hh = 0; hh < 4; ++hh) {
    const int h = w * 4 + hh;
    const size_t base = (size_t)tok * 3072 + h * 192 + 128;
    const float x  = bf2f(q[base + j]);
    const float xp = bf2f(q[base + partner]);
    q[base + j] = f2bf(x * c + sgn * xp * s);
  }
}

// ---------------- bf16 GEMM 128x128 (m97 structure), for small-N shapes ------
__global__ __launch_bounds__(256) void gemm_bt(const u16* __restrict__ A, const u16* __restrict__ B,
                                               u16* __restrict__ Cb, float* __restrict__ Cf,
                                               int M, int N, int K) {
  __shared__ __attribute__((aligned(16))) u16 As[128 * 64];
  __shared__ __attribute__((aligned(16))) u16 Bs[128 * 64];
  const int tid = threadIdx.x;
  const int m0 = blockIdx.y * 128, n0 = blockIdx.x * 128;
  const int w = tid >> 6, lane = tid & 63;
  const int wr = w >> 1, wc = w & 1;
  const int lr = lane & 15, g = lane >> 4;

  f32x4 acc[4][4] = {};

  for (int k0 = 0; k0 < K; k0 += 64) {
#pragma unroll
    for (int i = 0; i < 4; ++i) {
      const int c = i * 256 + tid;
      const int row = c >> 3, col = (c & 7) << 3;
      GLOAD16(A + (size_t)(m0 + row) * K + k0 + col, &As[c * 8]);
    }
#pragma unroll
    for (int i = 0; i < 4; ++i) {
      const int c = i * 256 + tid;
      const int row = c >> 3, col = (c & 7) << 3;
      GLOAD16(B + (size_t)(n0 + row) * K + k0 + col, &Bs[c * 8]);
    }
    __syncthreads();
    bf16x8 af[4][2], bfr[4][2];
#pragma unroll
    for (int x = 0; x < 4; ++x)
#pragma unroll
      for (int kk = 0; kk < 2; ++kk) {
        af[x][kk]  = *(const bf16x8*)(&As[(wr * 64 + x * 16 + lr) * 64 + kk * 32 + g * 8]);
        bfr[x][kk] = *(const bf16x8*)(&Bs[(wc * 64 + x * 16 + lr) * 64 + kk * 32 + g * 8]);
      }
#pragma unroll
    for (int mi = 0; mi < 4; ++mi)
#pragma unroll
      for (int ni = 0; ni < 4; ++ni)
#pragma unroll
        for (int kk = 0; kk < 2; ++kk)
          acc[mi][ni] = __builtin_amdgcn_mfma_f32_16x16x32_bf16(af[mi][kk], bfr[ni][kk],
                                                                acc[mi][ni], 0, 0, 0);
    __syncthreads();
  }

  const int rb = m0 + wr * 64, cb = n0 + wc * 64;
#pragma unroll
  for (int mi = 0; mi < 4; ++mi)
#pragma unroll
    for (int ni = 0; ni < 4; ++ni)
#pragma unroll
      for (int i = 0; i < 4; ++i) {
        const int r = rb + mi * 16 + g * 4 + i;
        const int cI = cb + ni * 16 + lr;
        if (Cf) Cf[(size_t)r * N + cI] = acc[mi][ni][i];
        else    Cb[(size_t)r * N + cI] = f2bf(acc[mi][ni][i]);
      }
}

// ---------------- bf16 GEMM 256x256, 8 waves, 4-phase K-tile pipeline --------
// BK=64, double-buffered 128KB LDS via global_load_lds (pre-swizzled source,
// XOR-swizzled ds_read -> conflict-free b128). Prefetch for tile t+1 issued at
// phase 1 of tile t (~3 phases before the single per-tile vmcnt(0) drain).
// Per phase: {A-frag ds_reads; lgkmcnt(0); sched_barrier; setprio(1); 16 MFMA;
// setprio(0); barrier}. Wave (wr,wc of 2x4) owns a 128x64 output panel.
__global__ __launch_bounds__(512) void gemm256(const u16* __restrict__ A, const u16* __restrict__ B,
                                               u16* __restrict__ Cb, float* __restrict__ Cf,
                                               int M, int N, int K) {
  __shared__ __attribute__((aligned(16))) u16 As[2][256 * 64];
  __shared__ __attribute__((aligned(16))) u16 Bs[2][256 * 64];
  const int tid = threadIdx.x;
  const int m0 = blockIdx.y * 256, n0 = blockIdx.x * 256;
  const int wid = tid >> 6, lane = tid & 63;
  const int wr = wid >> 2, wc = wid & 3;
  const int lr = lane & 15, g = lane >> 4;

  // staging: 4 A-chunks + 4 B-chunks per thread; source pre-swizzled cl^(row&7)
  const u16* pA[4];
  const u16* pB[4];
  int lOff[4];
#pragma unroll
  for (int i = 0; i < 4; ++i) {
    const int c = i * 512 + tid;               // 0..2047
    const int row = c >> 3, cl = c & 7;
    const int cg = cl ^ (row & 7);
    lOff[i] = c * 8;
    pA[i] = A + (size_t)(m0 + row) * K + cg * 8;
    pB[i] = B + (size_t)(n0 + row) * K + cg * 8;
  }

  // fragment read bases: row = (wr*128 | wc*64) + f*16 + lr; chunk = (kk*4+g)^(lr&7)
  const int aBase = (wr * 128 + lr) * 64;
  const int bBase = (wc * 64 + lr) * 64;
  int kch[2];
#pragma unroll
  for (int kk = 0; kk < 2; ++kk) kch[kk] = ((kk * 4 + g) ^ (lr & 7)) * 8;

  f32x4 acc[8][4] = {};
  const int nkt = K >> 6;

  // prologue: stage tile 0 into buf 0
#pragma unroll
  for (int i = 0; i < 4; ++i) GLOAD16(pA[i], &As[0][lOff[i]]);
#pragma unroll
  for (int i = 0; i < 4; ++i) GLOAD16(pB[i], &Bs[0][lOff[i]]);
#pragma unroll
  for (int i = 0; i < 4; ++i) { pA[i] += 64; pB[i] += 64; }
  asm volatile("s_waitcnt vmcnt(0)" ::: "memory");
  __builtin_amdgcn_s_barrier();
  __builtin_amdgcn_sched_barrier(0);

  for (int t = 0; t < nkt; ++t) {
    const int buf = t & 1;
    // phase 1 head: issue full prefetch of tile t+1 into buf^1
    if (t + 1 < nkt) {
#pragma unroll
      for (int i = 0; i < 4; ++i) GLOAD16(pA[i], &As[buf ^ 1][lOff[i]]);
#pragma unroll
      for (int i = 0; i < 4; ++i) GLOAD16(pB[i], &Bs[buf ^ 1][lOff[i]]);
#pragma unroll
      for (int i = 0; i < 4; ++i) { pA[i] += 64; pB[i] += 64; }
    }
    // B fragments for the whole tile (read once, phase 1)
    bf16x8 bfr[4][2];
#pragma unroll
    for (int fn = 0; fn < 4; ++fn)
#pragma unroll
      for (int kk = 0; kk < 2; ++kk)
        bfr[fn][kk] = *(const bf16x8*)(&Bs[buf][bBase + fn * 1024 + kch[kk]]);
    // 4 phases, each: 2 A-frag-rows x 4 B-cols x 2 ksubs = 16 MFMA
#pragma unroll
    for (int q = 0; q < 4; ++q) {
      bf16x8 afr[2][2];
#pragma unroll
      for (int fr = 0; fr < 2; ++fr)
#pragma unroll
        for (int kk = 0; kk < 2; ++kk)
          afr[fr][kk] = *(const bf16x8*)(&As[buf][aBase + (q * 2 + fr) * 1024 + kch[kk]]);
      asm volatile("s_waitcnt lgkmcnt(0)" ::: "memory");
      __builtin_amdgcn_sched_barrier(0);
      __builtin_amdgcn_s_setprio(1);
#pragma unroll
      for (int fr = 0; fr < 2; ++fr)
#pragma unroll
        for (int fn = 0; fn < 4; ++fn)
#pragma unroll
          for (int kk = 0; kk < 2; ++kk)
            acc[q * 2 + fr][fn] = __builtin_amdgcn_mfma_f32_16x16x32_bf16(
                afr[fr][kk], bfr[fn][kk], acc[q * 2 + fr][fn], 0, 0, 0);
      __builtin_amdgcn_s_setprio(0);
      if (q == 3) asm volatile("s_waitcnt vmcnt(0)" ::: "memory");
      __builtin_amdgcn_s_barrier();
    }
    __builtin_amdgcn_sched_barrier(0);
  }

  // epilogue
  const int rb = m0 + wr * 128, cb = n0 + wc * 64;
#pragma unroll
  for (int fm = 0; fm < 8; ++fm)
#pragma unroll
    for (int fn = 0; fn < 4; ++fn)
#pragma unroll
      for (int i = 0; i < 4; ++i) {
        const int r = rb + fm * 16 + g * 4 + i;
        const int cI = cb + fn * 16 + lr;
        if (Cf) Cf[(size_t)r * N + cI] = acc[fm][fn][i];
        else    Cb[(size_t)r * N + cI] = f2bf(acc[fm][fn][i]);
      }
}

// ---------------- V transpose: kvb V-half -> vT[bh*128+v][seq] ---------------
__global__ __launch_bounds__(256) void vtr_k(const u16* __restrict__ kvb, u16* __restrict__ vT) {
  __shared__ u16 tile[128 * 72];             // [v][s], stride 72 keeps b128 align
  const int bh = blockIdx.x, b = bh >> 4, h = bh & 15;
  const int s0 = blockIdx.y * 64;
  const int t = threadIdx.x;
  {
    const int s = t >> 2;                    // 0..63
    const int vc = (t & 3) * 32;             // 0,32,64,96
    const u16* src = kvb + (size_t)(b * 2048 + s0 + s) * 4096 + h * 256 + 128 + vc;
#pragma unroll
    for (int c = 0; c < 4; ++c) {
      u16x8 v = *(const u16x8*)(src + c * 8);
#pragma unroll
      for (int e = 0; e < 8; ++e) tile[(vc + c * 8 + e) * 72 + s] = v[e];
    }
  }
  __syncthreads();
  {
    const int v = t >> 1;                    // 0..127
    const int sh = (t & 1) * 32;
    u16* dst = vT + (size_t)(bh * 128 + v) * 2048 + s0 + sh;
    const u16* srow = &tile[v * 72 + sh];
#pragma unroll
    for (int c = 0; c < 4; ++c)
      *(u16x8*)(dst + c * 8) = *(const u16x8*)(srow + c * 8);
  }
}

// ---------------- causal flash attention, per (b,head) -----------------------
// r13 exact (best attn: 161us): heavy-first grid, KV tile 64, Ps aliases Ks,
// V staged from pre-transposed vT via linear global_load_lds.
__global__ __launch_bounds__(256) void attn_k(const u16* __restrict__ q, const u16* __restrict__ kvb,
                                              const u16* __restrict__ kpe, const u16* __restrict__ vT,
                                              u16* __restrict__ ao) {
  __shared__ __attribute__((aligned(16))) u16 Ks[64 * 192];   // also holds Ps after QK
  __shared__ __attribute__((aligned(16))) u16 Vt[128 * 64];   // [v][k-chunk swizzled]

  const float SCALE = 0.07216878364870323f;  // 192^-0.5
  const int bh = blockIdx.x;
  const int b = bh >> 4, h = bh & 15;
  const int j = 15 - blockIdx.y;             // heavy q-tiles dispatch first
  const int tid = threadIdx.x, w = tid >> 6, lane = tid & 63;
  const int lr = lane & 15, g = lane >> 4;

  const int q0 = j * 128;
  const int qrb = q0 + w * 32;
  u16* Psw = &Ks[w * 2304];                  // per-wave 32x72 slice inside Ks

  bf16x8 qf[2][6];
#pragma unroll
  for (int m = 0; m < 2; ++m)
#pragma unroll
    for (int kd = 0; kd < 6; ++kd)
      qf[m][kd] = *(const bf16x8*)(q + (size_t)(b * 2048 + qrb + m * 16 + lr) * 3072 +
                                   h * 192 + kd * 32 + g * 8);

  float mrow[2][4], lrow[2][4];
  f32x4 o[2][8] = {};
#pragma unroll
  for (int m = 0; m < 2; ++m)
#pragma unroll
    for (int i = 0; i < 4; ++i) { mrow[m][i] = -1e30f; lrow[m][i] = 0.f; }

  const int nt = (q0 >> 6) + 2;
  for (int t = 0; t < nt; ++t) {
    const int k0 = t * 64;
#pragma unroll
    for (int i = 0; i < 6; ++i) {
      const int c = i * 256 + tid;           // 0..1535
      const int row = c / 24, cl = c - row * 24;
      const int cg = cl ^ (row & 7);
      const u16* src = (cg < 16)
        ? (kvb + (size_t)(b * 2048 + k0 + row) * 4096 + h * 256 + cg * 8)
        : (kpe + (size_t)(b * 2048 + k0 + row) * 64 + (cg - 16) * 8);
      GLOAD16(src, &Ks[c * 8]);
    }
#pragma unroll
    for (int i = 0; i < 4; ++i) {
      const int c = i * 256 + tid;           // 0..1023
      const int v = c >> 3, cl = c & 7;
      const int cg = cl ^ (v & 7);
      GLOAD16(vT + (size_t)(bh * 128 + v) * 2048 + k0 + cg * 8, &Vt[c * 8]);
    }
    __syncthreads();

    const bool active = (k0 <= qrb + 31);    // wave-uniform
    f32x4 sAcc[2][4] = {};
    if (active) {
#pragma unroll
      for (int nf = 0; nf < 4; ++nf) {
        const int rr = nf * 16 + lr;
#pragma unroll
        for (int kd = 0; kd < 6; ++kd) {
          const int ch = (kd * 4 + g) ^ (rr & 7);
          const bf16x8 kf = *(const bf16x8*)(&Ks[rr * 192 + ch * 8]);
#pragma unroll
          for (int m = 0; m < 2; ++m)
            sAcc[m][nf] = __builtin_amdgcn_mfma_f32_16x16x32_bf16(qf[m][kd], kf, sAcc[m][nf], 0, 0, 0);
        }
      }
    }
    __syncthreads();                         // all Ks reads done; Ps may overwrite

    if (active) {
#pragma unroll
      for (int m = 0; m < 2; ++m) {
        float sv[4][4];
#pragma unroll
        for (int nf = 0; nf < 4; ++nf)
#pragma unroll
          for (int i = 0; i < 4; ++i) {
            const int qrow = qrb + m * 16 + g * 4 + i;
            const int kcol = k0 + nf * 16 + lr;
            const float vS = sAcc[m][nf][i] * SCALE;
            sv[nf][i] = (kcol > qrow) ? -1e30f : vS;
          }
        float fac[4], mn[4];
#pragma unroll
        for (int i = 0; i < 4; ++i) {
          float rm = fmaxf(fmaxf(sv[0][i], sv[1][i]), fmaxf(sv[2][i], sv[3][i]));
          rm = fmaxf(rm, __shfl_xor(rm, 1));
          rm = fmaxf(rm, __shfl_xor(rm, 2));
          rm = fmaxf(rm, __shfl_xor(rm, 4));
          rm = fmaxf(rm, __shfl_xor(rm, 8));
          mn[i] = fmaxf(mrow[m][i], rm);
          fac[i] = __expf(mrow[m][i] - mn[i]);
          mrow[m][i] = mn[i];
        }
#pragma unroll
        for (int i = 0; i < 4; ++i) {
          float rsum = 0.f;
#pragma unroll
          for (int nf = 0; nf < 4; ++nf) { sv[nf][i] = __expf(sv[nf][i] - mn[i]); rsum += sv[nf][i]; }
          rsum += __shfl_xor(rsum, 1);
          rsum += __shfl_xor(rsum, 2);
          rsum += __shfl_xor(rsum, 4);
          rsum += __shfl_xor(rsum, 8);
          lrow[m][i] = lrow[m][i] * fac[i] + rsum;
        }
#pragma unroll
        for (int nv = 0; nv < 8; ++nv)
#pragma unroll
          for (int i = 0; i < 4; ++i) o[m][nv][i] *= fac[i];
#pragma unroll
        for (int nf = 0; nf < 4; ++nf)
#pragma unroll
          for (int i = 0; i < 4; ++i)
            Psw[(m * 16 + g * 4 + i) * 72 + nf * 16 + lr] = f2bf(sv[nf][i]);
      }
      asm volatile("s_waitcnt lgkmcnt(0)" ::: "memory");

#pragma unroll
      for (int kc = 0; kc < 2; ++kc) {
        bf16x8 vfr[8];
#pragma unroll
        for (int nv = 0; nv < 8; ++nv) {
          const int v = nv * 16 + lr;
          const int cx = (kc * 4 + g) ^ (v & 7);
          vfr[nv] = *(const bf16x8*)(&Vt[v * 64 + cx * 8]);
        }
#pragma unroll
        for (int m = 0; m < 2; ++m) {
          const bf16x8 pf = *(const bf16x8*)(&Psw[(m * 16 + lr) * 72 + kc * 32 + g * 8]);
#pragma unroll
          for (int nv = 0; nv < 8; ++nv)
            o[m][nv] = __builtin_amdgcn_mfma_f32_16x16x32_bf16(pf, vfr[nv], o[m][nv], 0, 0, 0);
        }
      }
    }
    __syncthreads();                         // Ps/Vt reads done before next stage
  }

#pragma unroll
  for (int m = 0; m < 2; ++m)
#pragma unroll
    for (int i = 0; i < 4; ++i) {
      const float inv = 1.0f / lrow[m][i];
      const size_t tokOff = (size_t)(b * 2048 + qrb + m * 16 + g * 4 + i) * 2048 + h * 128;
#pragma unroll
      for (int nv = 0; nv < 8; ++nv)
        ao[tokOff + nv * 16 + lr] = f2bf(o[m][nv][i] * inv);
    }
}

// -----------------------------------------------------------------------------
extern "C" void kernel_launch(void* const* d_in, const int* in_sizes, int n_in,
                              void* d_out, int out_size, void* d_ws, size_t ws_size,
                              hipStream_t stream) {
  const float* hidden  = (const float*)d_in[0];
  const int*   pos     = (const int*)d_in[1];
  const float* q_a_w   = (const float*)d_in[2];
  const float* q_a_ln  = (const float*)d_in[3];
  const float* q_b_w   = (const float*)d_in[4];
  const float* kv_a_w  = (const float*)d_in[5];
  const float* kv_a_ln = (const float*)d_in[6];
  const float* kv_b_w  = (const float*)d_in[7];
  const float* o_w     = (const float*)d_in[8];
  float* out = (float*)d_out;

  char* ws = (char*)d_ws;
  u16* hb  = (u16*)(ws + 0L);          // 4096x2048 (reused as vT after kv_a gemm)
  u16* w1  = (u16*)(ws + 16777216L);   // 1536x2048
  u16* w2  = (u16*)(ws + 23068672L);   // 3072x1536
  u16* w3  = (u16*)(ws + 32505856L);   // 640x2048 (padded)
  u16* w4  = (u16*)(ws + 35127296L);   // 4096x512
  u16* w5  = (u16*)(ws + 39321600L);   // 2048x2048
  u16* qa  = (u16*)(ws + 47710208L);   // 4096x1536
  u16* qb  = (u16*)(ws + 60293120L);   // 4096x3072
  u16* kva = (u16*)(ws + 85458944L);   // 4096x640
  u16* ckv = (u16*)(ws + 90701824L);   // 4096x512
  u16* kpe = (u16*)(ws + 94896128L);   // 4096x64
  u16* kvb = (u16*)(ws + 95420416L);   // 4096x4096
  u16* ao  = (u16*)(ws + 128974848L);  // 4096x2048
  u16* vT  = hb;                       // 4096x2048, hb dead after kv_a gemm
  if (ws_size < 145752064UL) { fprintf(stderr, "ws too small: %zu\n", ws_size); return; }

  auto cvt = [&](const float* s, u16* d, long sn, long dn) {
    long blocks = (dn / 8 + 255) / 256; if (blocks > 2048) blocks = 2048;
    cvt_pad_k<<<dim3((unsigned)blocks), dim3(256), 0, stream>>>(s, d, sn, dn);
  };
  cvt(hidden, hb, 4096L * 2048, 4096L * 2048);
  cvt(q_a_w,  w1, 1536L * 2048, 1536L * 2048);
  cvt(q_b_w,  w2, 3072L * 1536, 3072L * 1536);
  cvt(kv_a_w, w3, 576L * 2048,  640L * 2048);
  cvt(kv_b_w, w4, 4096L * 512,  4096L * 512);
  cvt(o_w,    w5, 2048L * 2048, 2048L * 2048);

  gemm_bt<<<dim3(12, 32), 256, 0, stream>>>(hb, w1, qa, nullptr, 4096, 1536, 2048);
  rms_k<<<4096, 256, 0, stream>>>(qa, qa, q_a_ln, 1536, 1536, 1536);
  gemm256<<<dim3(12, 16), 512, 0, stream>>>(qa, w2, qb, nullptr, 4096, 3072, 1536);
  gemm_bt<<<dim3(5, 32), 256, 0, stream>>>(hb, w3, kva, nullptr, 4096, 640, 2048);
  rms_k<<<4096, 256, 0, stream>>>(kva, ckv, kv_a_ln, 640, 512, 512);
  rope_k<<<4096, 256, 0, stream>>>(qb, kva, kpe, pos);
  gemm256<<<dim3(16, 16), 512, 0, stream>>>(ckv, w4, kvb, nullptr, 4096, 4096, 512);
  vtr_k<<<dim3(32, 32), 256, 0, stream>>>(kvb, vT);
  attn_k<<<dim3(32, 16), 256, 0, stream>>>(qb, kvb, kpe, vT, ao);
  gemm256<<<dim3(8, 16), 512, 0, stream>>>(ao, w5, nullptr, out, 4096, 2048, 2048);
}

// Round 16
// 456.877 us; speedup vs baseline: 1.1148x; 1.0329x over previous
//
#include <hip/hip_runtime.h>
#include <cstdio>

typedef unsigned short u16;
typedef u16 u16x8 __attribute__((ext_vector_type(8)));
typedef __bf16 bf16x8 __attribute__((ext_vector_type(8)));
typedef float f32x4 __attribute__((ext_vector_type(4)));

#define AS1 __attribute__((address_space(1)))
#define AS3 __attribute__((address_space(3)))

#define GLOAD16(gsrc, ldst) __builtin_amdgcn_global_load_lds( \
    (const AS1 void*)(gsrc), (AS3 void*)(ldst), 16, 0, 0)

__device__ __forceinline__ u16 f2bf(float f) {
  unsigned u = __builtin_bit_cast(unsigned, f);
  u += 0x7fffu + ((u >> 16) & 1u);
  return (u16)(u >> 16);
}
__device__ __forceinline__ float bf2f(u16 h) {
  return __builtin_bit_cast(float, (unsigned)h << 16);
}

// ---------------- fp32 -> bf16 convert (with trailing-row zero pad) ----------
__global__ __launch_bounds__(256) void cvt_pad_k(const float* __restrict__ src,
                                                 u16* __restrict__ dst,
                                                 long srcN, long dstN) {
  long i = ((long)blockIdx.x * 256 + threadIdx.x) * 8;
  const long stride = (long)gridDim.x * 256 * 8;
  for (; i < dstN; i += stride) {
    u16x8 o = {0,0,0,0,0,0,0,0};
    if (i < srcN) {
      const float4* p = (const float4*)(src + i);
      float4 a = p[0], b = p[1];
      o[0]=f2bf(a.x); o[1]=f2bf(a.y); o[2]=f2bf(a.z); o[3]=f2bf(a.w);
      o[4]=f2bf(b.x); o[5]=f2bf(b.y); o[6]=f2bf(b.z); o[7]=f2bf(b.w);
    }
    *(u16x8*)(dst + i) = o;
  }
}

// ---------------- RMSNorm over last dim (bf16 in/out, fp32 math) -------------
__global__ __launch_bounds__(256) void rms_k(const u16* __restrict__ src, u16* __restrict__ dst,
                                             const float* __restrict__ w,
                                             int sstride, int dstride, int cols) {
  const int row = blockIdx.x;
  const int tid = threadIdx.x;
  const int nch = cols >> 3;
  float x[8];
  float ss = 0.f;
  if (tid < nch) {
    u16x8 v = *(const u16x8*)(src + (size_t)row * sstride + tid * 8);
#pragma unroll
    for (int j = 0; j < 8; ++j) { x[j] = bf2f(v[j]); ss += x[j] * x[j]; }
  } else {
#pragma unroll
    for (int j = 0; j < 8; ++j) x[j] = 0.f;
  }
#pragma unroll
  for (int off = 1; off < 64; off <<= 1) ss += __shfl_xor(ss, off);
  __shared__ float red[4];
  const int wv = tid >> 6, ln = tid & 63;
  if (ln == 0) red[wv] = ss;
  __syncthreads();
  const float tot = red[0] + red[1] + red[2] + red[3];
  const float rs = 1.0f / sqrtf(tot / (float)cols + 1e-6f);
  if (tid < nch) {
    u16x8 o;
#pragma unroll
    for (int j = 0; j < 8; ++j) o[j] = f2bf(x[j] * rs * w[tid * 8 + j]);
    *(u16x8*)(dst + (size_t)row * dstride + tid * 8) = o;
  }
}

// ---------------- RoPE: q_pe (in place, 16 heads) + k_pe -> kpe --------------
__global__ __launch_bounds__(256) void rope_k(u16* __restrict__ q, const u16* __restrict__ kva,
                                              u16* __restrict__ kpe, const int* __restrict__ pos) {
  const int tok = blockIdx.x;          // 0..4095
  const int j = threadIdx.x & 63;
  const int w = threadIdx.x >> 6;
  const float p = (float)pos[tok];
  const int jj = j & 31;
  const float inv = __powf(10000.0f, -(float)jj * (1.0f / 32.0f));
  float s, c;
  __sincosf(p * inv, &s, &c);
  const float sgn = (j < 32) ? -1.0f : 1.0f;
  const int partner = (j < 32) ? j + 32 : j - 32;
  if (w == 0) {
    const float x  = bf2f(kva[(size_t)tok * 640 + 512 + j]);
    const float xp = bf2f(kva[(size_t)tok * 640 + 512 + partner]);
    kpe[(size_t)tok * 64 + j] = f2bf(x * c + sgn * xp * s);
  }
#pragma unroll
  for (int hh = 0; hh < 4; ++hh) {
    const int h = w * 4 + hh;
    const size_t base = (size_t)tok * 3072 + h * 192 + 128;
    const float x  = bf2f(q[base + j]);
    const float xp = bf2f(q[base + partner]);
    q[base + j] = f2bf(x * c + sgn * xp * s);
  }
}

// ---------------- bf16 GEMM 128x128 (m97 structure), for small-N shapes ------
// cs: epilogue scale (folds attention's 192^-0.5 into the q_b GEMM for free)
__global__ __launch_bounds__(256) void gemm_bt(const u16* __restrict__ A, const u16* __restrict__ B,
                                               u16* __restrict__ Cb, float* __restrict__ Cf,
                                               int M, int N, int K, float cs) {
  __shared__ __attribute__((aligned(16))) u16 As[128 * 64];
  __shared__ __attribute__((aligned(16))) u16 Bs[128 * 64];
  const int tid = threadIdx.x;
  const int m0 = blockIdx.y * 128, n0 = blockIdx.x * 128;
  const int w = tid >> 6, lane = tid & 63;
  const int wr = w >> 1, wc = w & 1;
  const int lr = lane & 15, g = lane >> 4;

  f32x4 acc[4][4] = {};

  for (int k0 = 0; k0 < K; k0 += 64) {
#pragma unroll
    for (int i = 0; i < 4; ++i) {
      const int c = i * 256 + tid;
      const int row = c >> 3, col = (c & 7) << 3;
      GLOAD16(A + (size_t)(m0 + row) * K + k0 + col, &As[c * 8]);
    }
#pragma unroll
    for (int i = 0; i < 4; ++i) {
      const int c = i * 256 + tid;
      const int row = c >> 3, col = (c & 7) << 3;
      GLOAD16(B + (size_t)(n0 + row) * K + k0 + col, &Bs[c * 8]);
    }
    __syncthreads();
    bf16x8 af[4][2], bfr[4][2];
#pragma unroll
    for (int x = 0; x < 4; ++x)
#pragma unroll
      for (int kk = 0; kk < 2; ++kk) {
        af[x][kk]  = *(const bf16x8*)(&As[(wr * 64 + x * 16 + lr) * 64 + kk * 32 + g * 8]);
        bfr[x][kk] = *(const bf16x8*)(&Bs[(wc * 64 + x * 16 + lr) * 64 + kk * 32 + g * 8]);
      }
#pragma unroll
    for (int mi = 0; mi < 4; ++mi)
#pragma unroll
      for (int ni = 0; ni < 4; ++ni)
#pragma unroll
        for (int kk = 0; kk < 2; ++kk)
          acc[mi][ni] = __builtin_amdgcn_mfma_f32_16x16x32_bf16(af[mi][kk], bfr[ni][kk],
                                                                acc[mi][ni], 0, 0, 0);
    __syncthreads();
  }

  const int rb = m0 + wr * 64, cb = n0 + wc * 64;
#pragma unroll
  for (int mi = 0; mi < 4; ++mi)
#pragma unroll
    for (int ni = 0; ni < 4; ++ni)
#pragma unroll
      for (int i = 0; i < 4; ++i) {
        const int r = rb + mi * 16 + g * 4 + i;
        const int cI = cb + ni * 16 + lr;
        if (Cf) Cf[(size_t)r * N + cI] = acc[mi][ni][i] * cs;
        else    Cb[(size_t)r * N + cI] = f2bf(acc[mi][ni][i] * cs);
      }
}

// ---------------- bf16 GEMM 256x256, 8 waves, 4-phase K-tile pipeline --------
__global__ __launch_bounds__(512) void gemm256(const u16* __restrict__ A, const u16* __restrict__ B,
                                               u16* __restrict__ Cb, float* __restrict__ Cf,
                                               int M, int N, int K, float cs) {
  __shared__ __attribute__((aligned(16))) u16 As[2][256 * 64];
  __shared__ __attribute__((aligned(16))) u16 Bs[2][256 * 64];
  const int tid = threadIdx.x;
  const int m0 = blockIdx.y * 256, n0 = blockIdx.x * 256;
  const int wid = tid >> 6, lane = tid & 63;
  const int wr = wid >> 2, wc = wid & 3;
  const int lr = lane & 15, g = lane >> 4;

  const u16* pA[4];
  const u16* pB[4];
  int lOff[4];
#pragma unroll
  for (int i = 0; i < 4; ++i) {
    const int c = i * 512 + tid;               // 0..2047
    const int row = c >> 3, cl = c & 7;
    const int cg = cl ^ (row & 7);
    lOff[i] = c * 8;
    pA[i] = A + (size_t)(m0 + row) * K + cg * 8;
    pB[i] = B + (size_t)(n0 + row) * K + cg * 8;
  }

  const int aBase = (wr * 128 + lr) * 64;
  const int bBase = (wc * 64 + lr) * 64;
  int kch[2];
#pragma unroll
  for (int kk = 0; kk < 2; ++kk) kch[kk] = ((kk * 4 + g) ^ (lr & 7)) * 8;

  f32x4 acc[8][4] = {};
  const int nkt = K >> 6;

#pragma unroll
  for (int i = 0; i < 4; ++i) GLOAD16(pA[i], &As[0][lOff[i]]);
#pragma unroll
  for (int i = 0; i < 4; ++i) GLOAD16(pB[i], &Bs[0][lOff[i]]);
#pragma unroll
  for (int i = 0; i < 4; ++i) { pA[i] += 64; pB[i] += 64; }
  asm volatile("s_waitcnt vmcnt(0)" ::: "memory");
  __builtin_amdgcn_s_barrier();
  __builtin_amdgcn_sched_barrier(0);

  for (int t = 0; t < nkt; ++t) {
    const int buf = t & 1;
    if (t + 1 < nkt) {
#pragma unroll
      for (int i = 0; i < 4; ++i) GLOAD16(pA[i], &As[buf ^ 1][lOff[i]]);
#pragma unroll
      for (int i = 0; i < 4; ++i) GLOAD16(pB[i], &Bs[buf ^ 1][lOff[i]]);
#pragma unroll
      for (int i = 0; i < 4; ++i) { pA[i] += 64; pB[i] += 64; }
    }
    bf16x8 bfr[4][2];
#pragma unroll
    for (int fn = 0; fn < 4; ++fn)
#pragma unroll
      for (int kk = 0; kk < 2; ++kk)
        bfr[fn][kk] = *(const bf16x8*)(&Bs[buf][bBase + fn * 1024 + kch[kk]]);
#pragma unroll
    for (int q = 0; q < 4; ++q) {
      bf16x8 afr[2][2];
#pragma unroll
      for (int fr = 0; fr < 2; ++fr)
#pragma unroll
        for (int kk = 0; kk < 2; ++kk)
          afr[fr][kk] = *(const bf16x8*)(&As[buf][aBase + (q * 2 + fr) * 1024 + kch[kk]]);
      asm volatile("s_waitcnt lgkmcnt(0)" ::: "memory");
      __builtin_amdgcn_sched_barrier(0);
      __builtin_amdgcn_s_setprio(1);
#pragma unroll
      for (int fr = 0; fr < 2; ++fr)
#pragma unroll
        for (int fn = 0; fn < 4; ++fn)
#pragma unroll
          for (int kk = 0; kk < 2; ++kk)
            acc[q * 2 + fr][fn] = __builtin_amdgcn_mfma_f32_16x16x32_bf16(
                afr[fr][kk], bfr[fn][kk], acc[q * 2 + fr][fn], 0, 0, 0);
      __builtin_amdgcn_s_setprio(0);
      if (q == 3) asm volatile("s_waitcnt vmcnt(0)" ::: "memory");
      __builtin_amdgcn_s_barrier();
    }
    __builtin_amdgcn_sched_barrier(0);
  }

  const int rb = m0 + wr * 128, cb = n0 + wc * 64;
#pragma unroll
  for (int fm = 0; fm < 8; ++fm)
#pragma unroll
    for (int fn = 0; fn < 4; ++fn)
#pragma unroll
      for (int i = 0; i < 4; ++i) {
        const int r = rb + fm * 16 + g * 4 + i;
        const int cI = cb + fn * 16 + lr;
        if (Cf) Cf[(size_t)r * N + cI] = acc[fm][fn][i] * cs;
        else    Cb[(size_t)r * N + cI] = f2bf(acc[fm][fn][i] * cs);
      }
}

// ---------------- V transpose: kvb V-half -> vT[bh*128+v][seq] ---------------
__global__ __launch_bounds__(256) void vtr_k(const u16* __restrict__ kvb, u16* __restrict__ vT) {
  __shared__ u16 tile[128 * 72];             // [v][s], stride 72 keeps b128 align
  const int bh = blockIdx.x, b = bh >> 4, h = bh & 15;
  const int s0 = blockIdx.y * 64;
  const int t = threadIdx.x;
  {
    const int s = t >> 2;                    // 0..63
    const int vc = (t & 3) * 32;             // 0,32,64,96
    const u16* src = kvb + (size_t)(b * 2048 + s0 + s) * 4096 + h * 256 + 128 + vc;
#pragma unroll
    for (int c = 0; c < 4; ++c) {
      u16x8 v = *(const u16x8*)(src + c * 8);
#pragma unroll
      for (int e = 0; e < 8; ++e) tile[(vc + c * 8 + e) * 72 + s] = v[e];
    }
  }
  __syncthreads();
  {
    const int v = t >> 1;                    // 0..127
    const int sh = (t & 1) * 32;
    u16* dst = vT + (size_t)(bh * 128 + v) * 2048 + s0 + sh;
    const u16* srow = &tile[v * 72 + sh];
#pragma unroll
    for (int c = 0; c < 4; ++c)
      *(u16x8*)(dst + c * 8) = *(const u16x8*)(srow + c * 8);
  }
}

// ---------------- causal flash attention, per (b,head) -----------------------
// r13/r15 template + this round: Q pre-scaled in q_b GEMM (no per-tile SCALE
// mult), diagonal-only masking (wave-uniform needMask), T13 defer-max (THR=8),
// T5 setprio around MFMA clusters.
__global__ __launch_bounds__(256) void attn_k(const u16* __restrict__ q, const u16* __restrict__ kvb,
                                              const u16* __restrict__ kpe, const u16* __restrict__ vT,
                                              u16* __restrict__ ao) {
  __shared__ __attribute__((aligned(16))) u16 Ks[64 * 192];   // also holds Ps after QK
  __shared__ __attribute__((aligned(16))) u16 Vt[128 * 64];   // [v][k-chunk swizzled]

  const int bh = blockIdx.x;
  const int b = bh >> 4, h = bh & 15;
  const int j = 15 - blockIdx.y;             // heavy q-tiles dispatch first
  const int tid = threadIdx.x, w = tid >> 6, lane = tid & 63;
  const int lr = lane & 15, g = lane >> 4;

  const int q0 = j * 128;
  const int qrb = q0 + w * 32;
  u16* Psw = &Ks[w * 2304];                  // per-wave 32x72 slice inside Ks

  bf16x8 qf[2][6];
#pragma unroll
  for (int m = 0; m < 2; ++m)
#pragma unroll
    for (int kd = 0; kd < 6; ++kd)
      qf[m][kd] = *(const bf16x8*)(q + (size_t)(b * 2048 + qrb + m * 16 + lr) * 3072 +
                                   h * 192 + kd * 32 + g * 8);

  float mrow[2][4], lrow[2][4];
  f32x4 o[2][8] = {};
#pragma unroll
  for (int m = 0; m < 2; ++m)
#pragma unroll
    for (int i = 0; i < 4; ++i) { mrow[m][i] = -1e30f; lrow[m][i] = 0.f; }

  const int nt = (q0 >> 6) + 2;
  for (int t = 0; t < nt; ++t) {
    const int k0 = t * 64;
#pragma unroll
    for (int i = 0; i < 6; ++i) {
      const int c = i * 256 + tid;           // 0..1535
      const int row = c / 24, cl = c - row * 24;
      const int cg = cl ^ (row & 7);
      const u16* src = (cg < 16)
        ? (kvb + (size_t)(b * 2048 + k0 + row) * 4096 + h * 256 + cg * 8)
        : (kpe + (size_t)(b * 2048 + k0 + row) * 64 + (cg - 16) * 8);
      GLOAD16(src, &Ks[c * 8]);
    }
#pragma unroll
    for (int i = 0; i < 4; ++i) {
      const int c = i * 256 + tid;           // 0..1023
      const int v = c >> 3, cl = c & 7;
      const int cg = cl ^ (v & 7);
      GLOAD16(vT + (size_t)(bh * 128 + v) * 2048 + k0 + cg * 8, &Vt[c * 8]);
    }
    __syncthreads();

    const bool active = (k0 <= qrb + 31);    // wave-uniform
    f32x4 sAcc[2][4] = {};
    if (active) {
      __builtin_amdgcn_s_setprio(1);
#pragma unroll
      for (int nf = 0; nf < 4; ++nf) {
        const int rr = nf * 16 + lr;
#pragma unroll
        for (int kd = 0; kd < 6; ++kd) {
          const int ch = (kd * 4 + g) ^ (rr & 7);
          const bf16x8 kf = *(const bf16x8*)(&Ks[rr * 192 + ch * 8]);
#pragma unroll
          for (int m = 0; m < 2; ++m)
            sAcc[m][nf] = __builtin_amdgcn_mfma_f32_16x16x32_bf16(qf[m][kd], kf, sAcc[m][nf], 0, 0, 0);
        }
      }
      __builtin_amdgcn_s_setprio(0);
    }
    __syncthreads();                         // all Ks reads done; Ps may overwrite

    if (active) {
      const bool needMask = (k0 + 63 > qrb); // wave-uniform: diagonal tiles only
#pragma unroll
      for (int m = 0; m < 2; ++m) {
        float sv[4][4];
        if (needMask) {
#pragma unroll
          for (int nf = 0; nf < 4; ++nf)
#pragma unroll
            for (int i = 0; i < 4; ++i) {
              const int qrow = qrb + m * 16 + g * 4 + i;
              const int kcol = k0 + nf * 16 + lr;
              sv[nf][i] = (kcol > qrow) ? -1e30f : sAcc[m][nf][i];
            }
        } else {
#pragma unroll
          for (int nf = 0; nf < 4; ++nf)
#pragma unroll
            for (int i = 0; i < 4; ++i) sv[nf][i] = sAcc[m][nf][i];
        }
        float rm4[4];
        bool exceed = false;
#pragma unroll
        for (int i = 0; i < 4; ++i) {
          float rm = fmaxf(fmaxf(sv[0][i], sv[1][i]), fmaxf(sv[2][i], sv[3][i]));
          rm = fmaxf(rm, __shfl_xor(rm, 1));
          rm = fmaxf(rm, __shfl_xor(rm, 2));
          rm = fmaxf(rm, __shfl_xor(rm, 4));
          rm = fmaxf(rm, __shfl_xor(rm, 8));
          rm4[i] = rm;
          exceed = exceed || (rm > mrow[m][i] + 8.0f);
        }
        if (__any(exceed)) {                 // T13: rescale only on real max growth
#pragma unroll
          for (int i = 0; i < 4; ++i) {
            const float mn = fmaxf(mrow[m][i], rm4[i]);
            const float fac = __expf(mrow[m][i] - mn);
            mrow[m][i] = mn;
            lrow[m][i] *= fac;
#pragma unroll
            for (int nv = 0; nv < 8; ++nv) o[m][nv][i] *= fac;
          }
        }
#pragma unroll
        for (int i = 0; i < 4; ++i) {
          float rsum = 0.f;
#pragma unroll
          for (int nf = 0; nf < 4; ++nf) { sv[nf][i] = __expf(sv[nf][i] - mrow[m][i]); rsum += sv[nf][i]; }
          rsum += __shfl_xor(rsum, 1);
          rsum += __shfl_xor(rsum, 2);
          rsum += __shfl_xor(rsum, 4);
          rsum += __shfl_xor(rsum, 8);
          lrow[m][i] += rsum;
        }
#pragma unroll
        for (int nf = 0; nf < 4; ++nf)
#pragma unroll
          for (int i = 0; i < 4; ++i)
            Psw[(m * 16 + g * 4 + i) * 72 + nf * 16 + lr] = f2bf(sv[nf][i]);
      }
      asm volatile("s_waitcnt lgkmcnt(0)" ::: "memory");

      __builtin_amdgcn_s_setprio(1);
#pragma unroll
      for (int kc = 0; kc < 2; ++kc) {
        bf16x8 vfr[8];
#pragma unroll
        for (int nv = 0; nv < 8; ++nv) {
          const int v = nv * 16 + lr;
          const int cx = (kc * 4 + g) ^ (v & 7);
          vfr[nv] = *(const bf16x8*)(&Vt[v * 64 + cx * 8]);
        }
#pragma unroll
        for (int m = 0; m < 2; ++m) {
          const bf16x8 pf = *(const bf16x8*)(&Psw[(m * 16 + lr) * 72 + kc * 32 + g * 8]);
#pragma unroll
          for (int nv = 0; nv < 8; ++nv)
            o[m][nv] = __builtin_amdgcn_mfma_f32_16x16x32_bf16(pf, vfr[nv], o[m][nv], 0, 0, 0);
        }
      }
      __builtin_amdgcn_s_setprio(0);
    }
    __syncthreads();                         // Ps/Vt reads done before next stage
  }

#pragma unroll
  for (int m = 0; m < 2; ++m)
#pragma unroll
    for (int i = 0; i < 4; ++i) {
      const float inv = 1.0f / lrow[m][i];
      const size_t tokOff = (size_t)(b * 2048 + qrb + m * 16 + g * 4 + i) * 2048 + h * 128;
#pragma unroll
      for (int nv = 0; nv < 8; ++nv)
        ao[tokOff + nv * 16 + lr] = f2bf(o[m][nv][i] * inv);
    }
}

// -----------------------------------------------------------------------------
extern "C" void kernel_launch(void* const* d_in, const int* in_sizes, int n_in,
                              void* d_out, int out_size, void* d_ws, size_t ws_size,
                              hipStream_t stream) {
  const float* hidden  = (const float*)d_in[0];
  const int*   pos     = (const int*)d_in[1];
  const float* q_a_w   = (const float*)d_in[2];
  const float* q_a_ln  = (const float*)d_in[3];
  const float* q_b_w   = (const float*)d_in[4];
  const float* kv_a_w  = (const float*)d_in[5];
  const float* kv_a_ln = (const float*)d_in[6];
  const float* kv_b_w  = (const float*)d_in[7];
  const float* o_w     = (const float*)d_in[8];
  float* out = (float*)d_out;

  char* ws = (char*)d_ws;
  u16* hb  = (u16*)(ws + 0L);          // 4096x2048 (reused as vT after kv_a gemm)
  u16* w1  = (u16*)(ws + 16777216L);   // 1536x2048
  u16* w2  = (u16*)(ws + 23068672L);   // 3072x1536
  u16* w3  = (u16*)(ws + 32505856L);   // 640x2048 (padded)
  u16* w4  = (u16*)(ws + 35127296L);   // 4096x512
  u16* w5  = (u16*)(ws + 39321600L);   // 2048x2048
  u16* qa  = (u16*)(ws + 47710208L);   // 4096x1536
  u16* qb  = (u16*)(ws + 60293120L);   // 4096x3072
  u16* kva = (u16*)(ws + 85458944L);   // 4096x640
  u16* ckv = (u16*)(ws + 90701824L);   // 4096x512
  u16* kpe = (u16*)(ws + 94896128L);   // 4096x64
  u16* kvb = (u16*)(ws + 95420416L);   // 4096x4096
  u16* ao  = (u16*)(ws + 128974848L);  // 4096x2048
  u16* vT  = hb;                       // 4096x2048, hb dead after kv_a gemm
  if (ws_size < 145752064UL) { fprintf(stderr, "ws too small: %zu\n", ws_size); return; }

  const float SCALE = 0.07216878364870323f;  // 192^-0.5, folded into q_b GEMM

  auto cvt = [&](const float* s, u16* d, long sn, long dn) {
    long blocks = (dn / 8 + 255) / 256; if (blocks > 2048) blocks = 2048;
    cvt_pad_k<<<dim3((unsigned)blocks), dim3(256), 0, stream>>>(s, d, sn, dn);
  };
  cvt(hidden, hb, 4096L * 2048, 4096L * 2048);
  cvt(q_a_w,  w1, 1536L * 2048, 1536L * 2048);
  cvt(q_b_w,  w2, 3072L * 1536, 3072L * 1536);
  cvt(kv_a_w, w3, 576L * 2048,  640L * 2048);
  cvt(kv_b_w, w4, 4096L * 512,  4096L * 512);
  cvt(o_w,    w5, 2048L * 2048, 2048L * 2048);

  gemm_bt<<<dim3(12, 32), 256, 0, stream>>>(hb, w1, qa, nullptr, 4096, 1536, 2048, 1.0f);
  rms_k<<<4096, 256, 0, stream>>>(qa, qa, q_a_ln, 1536, 1536, 1536);
  gemm256<<<dim3(12, 16), 512, 0, stream>>>(qa, w2, qb, nullptr, 4096, 3072, 1536, SCALE);
  gemm_bt<<<dim3(5, 32), 256, 0, stream>>>(hb, w3, kva, nullptr, 4096, 640, 2048, 1.0f);
  rms_k<<<4096, 256, 0, stream>>>(kva, ckv, kv_a_ln, 640, 512, 512);
  rope_k<<<4096, 256, 0, stream>>>(qb, kva, kpe, pos);
  gemm256<<<dim3(16, 16), 512, 0, stream>>>(ckv, w4, kvb, nullptr, 4096, 4096, 512, 1.0f);
  vtr_k<<<dim3(32, 32), 256, 0, stream>>>(kvb, vT);
  attn_k<<<dim3(32, 16), 256, 0, stream>>>(qb, kvb, kpe, vT, ao);
  gemm256<<<dim3(8, 16), 512, 0, stream>>>(ao, w5, nullptr, out, 4096, 2048, 2048, 1.0f);
}

// Round 17
// 432.876 us; speedup vs baseline: 1.1766x; 1.0554x over previous
//
#include <hip/hip_runtime.h>
#include <cstdio>

typedef unsigned short u16;
typedef u16 u16x8 __attribute__((ext_vector_type(8)));
typedef __bf16 bf16x8 __attribute__((ext_vector_type(8)));
typedef float f32x4 __attribute__((ext_vector_type(4)));

#define AS1 __attribute__((address_space(1)))
#define AS3 __attribute__((address_space(3)))

#define GLOAD16(gsrc, ldst) __builtin_amdgcn_global_load_lds( \
    (const AS1 void*)(gsrc), (AS3 void*)(ldst), 16, 0, 0)

__device__ __forceinline__ u16 f2bf(float f) {
  unsigned u = __builtin_bit_cast(unsigned, f);
  u += 0x7fffu + ((u >> 16) & 1u);
  return (u16)(u >> 16);
}
__device__ __forceinline__ float bf2f(u16 h) {
  return __builtin_bit_cast(float, (unsigned)h << 16);
}

// ---------------- fp32 -> bf16 convert (with trailing-row zero pad) ----------
__global__ __launch_bounds__(256) void cvt_pad_k(const float* __restrict__ src,
                                                 u16* __restrict__ dst,
                                                 long srcN, long dstN) {
  long i = ((long)blockIdx.x * 256 + threadIdx.x) * 8;
  const long stride = (long)gridDim.x * 256 * 8;
  for (; i < dstN; i += stride) {
    u16x8 o = {0,0,0,0,0,0,0,0};
    if (i < srcN) {
      const float4* p = (const float4*)(src + i);
      float4 a = p[0], b = p[1];
      o[0]=f2bf(a.x); o[1]=f2bf(a.y); o[2]=f2bf(a.z); o[3]=f2bf(a.w);
      o[4]=f2bf(b.x); o[5]=f2bf(b.y); o[6]=f2bf(b.z); o[7]=f2bf(b.w);
    }
    *(u16x8*)(dst + i) = o;
  }
}

// ---------------- RMSNorm over last dim (bf16 in/out, fp32 math) -------------
__global__ __launch_bounds__(256) void rms_k(const u16* __restrict__ src, u16* __restrict__ dst,
                                             const float* __restrict__ w,
                                             int sstride, int dstride, int cols) {
  const int row = blockIdx.x;
  const int tid = threadIdx.x;
  const int nch = cols >> 3;
  float x[8];
  float ss = 0.f;
  if (tid < nch) {
    u16x8 v = *(const u16x8*)(src + (size_t)row * sstride + tid * 8);
#pragma unroll
    for (int j = 0; j < 8; ++j) { x[j] = bf2f(v[j]); ss += x[j] * x[j]; }
  } else {
#pragma unroll
    for (int j = 0; j < 8; ++j) x[j] = 0.f;
  }
#pragma unroll
  for (int off = 1; off < 64; off <<= 1) ss += __shfl_xor(ss, off);
  __shared__ float red[4];
  const int wv = tid >> 6, ln = tid & 63;
  if (ln == 0) red[wv] = ss;
  __syncthreads();
  const float tot = red[0] + red[1] + red[2] + red[3];
  const float rs = 1.0f / sqrtf(tot / (float)cols + 1e-6f);
  if (tid < nch) {
    u16x8 o;
#pragma unroll
    for (int j = 0; j < 8; ++j) o[j] = f2bf(x[j] * rs * w[tid * 8 + j]);
    *(u16x8*)(dst + (size_t)row * dstride + tid * 8) = o;
  }
}

// ---------------- RoPE: q_pe (in place, 16 heads) + k_pe -> kpe --------------
// k_pe source now lives in the fused a-GEMM output qk_a (stride 2176, col 2048)
__global__ __launch_bounds__(256) void rope_k(u16* __restrict__ q, const u16* __restrict__ qk_a,
                                              u16* __restrict__ kpe, const int* __restrict__ pos) {
  const int tok = blockIdx.x;          // 0..4095
  const int j = threadIdx.x & 63;
  const int w = threadIdx.x >> 6;
  const float p = (float)pos[tok];
  const int jj = j & 31;
  const float inv = __powf(10000.0f, -(float)jj * (1.0f / 32.0f));
  float s, c;
  __sincosf(p * inv, &s, &c);
  const float sgn = (j < 32) ? -1.0f : 1.0f;
  const int partner = (j < 32) ? j + 32 : j - 32;
  if (w == 0) {
    const float x  = bf2f(qk_a[(size_t)tok * 2176 + 2048 + j]);
    const float xp = bf2f(qk_a[(size_t)tok * 2176 + 2048 + partner]);
    kpe[(size_t)tok * 64 + j] = f2bf(x * c + sgn * xp * s);
  }
#pragma unroll
  for (int hh = 0; hh < 4; ++hh) {
    const int h = w * 4 + hh;
    const size_t base = (size_t)tok * 3072 + h * 192 + 128;
    const float x  = bf2f(q[base + j]);
    const float xp = bf2f(q[base + partner]);
    q[base + j] = f2bf(x * c + sgn * xp * s);
  }
}

// ---------------- bf16 GEMM 128x128 (m97 structure) --------------------------
__global__ __launch_bounds__(256) void gemm_bt(const u16* __restrict__ A, const u16* __restrict__ B,
                                               u16* __restrict__ Cb, float* __restrict__ Cf,
                                               int M, int N, int K, float cs) {
  __shared__ __attribute__((aligned(16))) u16 As[128 * 64];
  __shared__ __attribute__((aligned(16))) u16 Bs[128 * 64];
  const int tid = threadIdx.x;
  const int m0 = blockIdx.y * 128, n0 = blockIdx.x * 128;
  const int w = tid >> 6, lane = tid & 63;
  const int wr = w >> 1, wc = w & 1;
  const int lr = lane & 15, g = lane >> 4;

  f32x4 acc[4][4] = {};

  for (int k0 = 0; k0 < K; k0 += 64) {
#pragma unroll
    for (int i = 0; i < 4; ++i) {
      const int c = i * 256 + tid;
      const int row = c >> 3, col = (c & 7) << 3;
      GLOAD16(A + (size_t)(m0 + row) * K + k0 + col, &As[c * 8]);
    }
#pragma unroll
    for (int i = 0; i < 4; ++i) {
      const int c = i * 256 + tid;
      const int row = c >> 3, col = (c & 7) << 3;
      GLOAD16(B + (size_t)(n0 + row) * K + k0 + col, &Bs[c * 8]);
    }
    __syncthreads();
    bf16x8 af[4][2], bfr[4][2];
#pragma unroll
    for (int x = 0; x < 4; ++x)
#pragma unroll
      for (int kk = 0; kk < 2; ++kk) {
        af[x][kk]  = *(const bf16x8*)(&As[(wr * 64 + x * 16 + lr) * 64 + kk * 32 + g * 8]);
        bfr[x][kk] = *(const bf16x8*)(&Bs[(wc * 64 + x * 16 + lr) * 64 + kk * 32 + g * 8]);
      }
#pragma unroll
    for (int mi = 0; mi < 4; ++mi)
#pragma unroll
      for (int ni = 0; ni < 4; ++ni)
#pragma unroll
        for (int kk = 0; kk < 2; ++kk)
          acc[mi][ni] = __builtin_amdgcn_mfma_f32_16x16x32_bf16(af[mi][kk], bfr[ni][kk],
                                                                acc[mi][ni], 0, 0, 0);
    __syncthreads();
  }

  const int rb = m0 + wr * 64, cb = n0 + wc * 64;
#pragma unroll
  for (int mi = 0; mi < 4; ++mi)
#pragma unroll
    for (int ni = 0; ni < 4; ++ni)
#pragma unroll
      for (int i = 0; i < 4; ++i) {
        const int r = rb + mi * 16 + g * 4 + i;
        const int cI = cb + ni * 16 + lr;
        if (Cf) Cf[(size_t)r * N + cI] = acc[mi][ni][i] * cs;
        else    Cb[(size_t)r * N + cI] = f2bf(acc[mi][ni][i] * cs);
      }
}

// ---------------- bf16 GEMM 256x256, 8 waves, 4-phase K-tile pipeline --------
__global__ __launch_bounds__(512) void gemm256(const u16* __restrict__ A, const u16* __restrict__ B,
                                               u16* __restrict__ Cb, float* __restrict__ Cf,
                                               int M, int N, int K, float cs) {
  __shared__ __attribute__((aligned(16))) u16 As[2][256 * 64];
  __shared__ __attribute__((aligned(16))) u16 Bs[2][256 * 64];
  const int tid = threadIdx.x;
  const int m0 = blockIdx.y * 256, n0 = blockIdx.x * 256;
  const int wid = tid >> 6, lane = tid & 63;
  const int wr = wid >> 2, wc = wid & 3;
  const int lr = lane & 15, g = lane >> 4;

  const u16* pA[4];
  const u16* pB[4];
  int lOff[4];
#pragma unroll
  for (int i = 0; i < 4; ++i) {
    const int c = i * 512 + tid;               // 0..2047
    const int row = c >> 3, cl = c & 7;
    const int cg = cl ^ (row & 7);
    lOff[i] = c * 8;
    pA[i] = A + (size_t)(m0 + row) * K + cg * 8;
    pB[i] = B + (size_t)(n0 + row) * K + cg * 8;
  }

  const int aBase = (wr * 128 + lr) * 64;
  const int bBase = (wc * 64 + lr) * 64;
  int kch[2];
#pragma unroll
  for (int kk = 0; kk < 2; ++kk) kch[kk] = ((kk * 4 + g) ^ (lr & 7)) * 8;

  f32x4 acc[8][4] = {};
  const int nkt = K >> 6;

#pragma unroll
  for (int i = 0; i < 4; ++i) GLOAD16(pA[i], &As[0][lOff[i]]);
#pragma unroll
  for (int i = 0; i < 4; ++i) GLOAD16(pB[i], &Bs[0][lOff[i]]);
#pragma unroll
  for (int i = 0; i < 4; ++i) { pA[i] += 64; pB[i] += 64; }
  asm volatile("s_waitcnt vmcnt(0)" ::: "memory");
  __builtin_amdgcn_s_barrier();
  __builtin_amdgcn_sched_barrier(0);

  for (int t = 0; t < nkt; ++t) {
    const int buf = t & 1;
    if (t + 1 < nkt) {
#pragma unroll
      for (int i = 0; i < 4; ++i) GLOAD16(pA[i], &As[buf ^ 1][lOff[i]]);
#pragma unroll
      for (int i = 0; i < 4; ++i) GLOAD16(pB[i], &Bs[buf ^ 1][lOff[i]]);
#pragma unroll
      for (int i = 0; i < 4; ++i) { pA[i] += 64; pB[i] += 64; }
    }
    bf16x8 bfr[4][2];
#pragma unroll
    for (int fn = 0; fn < 4; ++fn)
#pragma unroll
      for (int kk = 0; kk < 2; ++kk)
        bfr[fn][kk] = *(const bf16x8*)(&Bs[buf][bBase + fn * 1024 + kch[kk]]);
#pragma unroll
    for (int q = 0; q < 4; ++q) {
      bf16x8 afr[2][2];
#pragma unroll
      for (int fr = 0; fr < 2; ++fr)
#pragma unroll
        for (int kk = 0; kk < 2; ++kk)
          afr[fr][kk] = *(const bf16x8*)(&As[buf][aBase + (q * 2 + fr) * 1024 + kch[kk]]);
      asm volatile("s_waitcnt lgkmcnt(0)" ::: "memory");
      __builtin_amdgcn_sched_barrier(0);
      __builtin_amdgcn_s_setprio(1);
#pragma unroll
      for (int fr = 0; fr < 2; ++fr)
#pragma unroll
        for (int fn = 0; fn < 4; ++fn)
#pragma unroll
          for (int kk = 0; kk < 2; ++kk)
            acc[q * 2 + fr][fn] = __builtin_amdgcn_mfma_f32_16x16x32_bf16(
                afr[fr][kk], bfr[fn][kk], acc[q * 2 + fr][fn], 0, 0, 0);
      __builtin_amdgcn_s_setprio(0);
      if (q == 3) asm volatile("s_waitcnt vmcnt(0)" ::: "memory");
      __builtin_amdgcn_s_barrier();
    }
    __builtin_amdgcn_sched_barrier(0);
  }

  const int rb = m0 + wr * 128, cb = n0 + wc * 64;
#pragma unroll
  for (int fm = 0; fm < 8; ++fm)
#pragma unroll
    for (int fn = 0; fn < 4; ++fn)
#pragma unroll
      for (int i = 0; i < 4; ++i) {
        const int r = rb + fm * 16 + g * 4 + i;
        const int cI = cb + fn * 16 + lr;
        if (Cf) Cf[(size_t)r * N + cI] = acc[fm][fn][i] * cs;
        else    Cb[(size_t)r * N + cI] = f2bf(acc[fm][fn][i] * cs);
      }
}

// ---------------- V transpose: kvb V-half -> vT[bh*128+v][seq] ---------------
__global__ __launch_bounds__(256) void vtr_k(const u16* __restrict__ kvb, u16* __restrict__ vT) {
  __shared__ u16 tile[128 * 72];             // [v][s], stride 72 keeps b128 align
  const int bh = blockIdx.x, b = bh >> 4, h = bh & 15;
  const int s0 = blockIdx.y * 64;
  const int t = threadIdx.x;
  {
    const int s = t >> 2;                    // 0..63
    const int vc = (t & 3) * 32;             // 0,32,64,96
    const u16* src = kvb + (size_t)(b * 2048 + s0 + s) * 4096 + h * 256 + 128 + vc;
#pragma unroll
    for (int c = 0; c < 4; ++c) {
      u16x8 v = *(const u16x8*)(src + c * 8);
#pragma unroll
      for (int e = 0; e < 8; ++e) tile[(vc + c * 8 + e) * 72 + s] = v[e];
    }
  }
  __syncthreads();
  {
    const int v = t >> 1;                    // 0..127
    const int sh = (t & 1) * 32;
    u16* dst = vT + (size_t)(bh * 128 + v) * 2048 + s0 + sh;
    const u16* srow = &tile[v * 72 + sh];
#pragma unroll
    for (int c = 0; c < 4; ++c)
      *(u16x8*)(dst + c * 8) = *(const u16x8*)(srow + c * 8);
  }
}

// ---------------- causal flash attention, per (b,head) -----------------------
// r16 + this round: Ps has its own buffer (mid-tile barrier removed; 2
// barriers/tile), staging addresses hoisted to int32 offsets off one base
// (kvb = kpe + 262144 elements by ws layout). Q pre-scaled; defer-max;
// diagonal-only masking; setprio around MFMA clusters.
__global__ __launch_bounds__(256) void attn_k(const u16* __restrict__ q, const u16* __restrict__ kpe,
                                              const u16* __restrict__ vT, u16* __restrict__ ao) {
  __shared__ __attribute__((aligned(16))) u16 Ks[64 * 192];
  __shared__ __attribute__((aligned(16))) u16 Vt[128 * 64];
  __shared__ __attribute__((aligned(16))) u16 Ps[4][32 * 72];

  const int bh = blockIdx.x;
  const int b = bh >> 4, h = bh & 15;
  const int j = 15 - blockIdx.y;             // heavy q-tiles dispatch first (LPT)
  const int tid = threadIdx.x, w = tid >> 6, lane = tid & 63;
  const int lr = lane & 15, g = lane >> 4;

  const int q0 = j * 128;
  const int qrb = q0 + w * 32;
  u16* Psw = &Ps[w][0];

  // hoisted K staging offsets (elements from kpe base; kvb = kpe + 262144)
  int koff[6], kstep[6], kld[6];
#pragma unroll
  for (int i = 0; i < 6; ++i) {
    const int c = i * 256 + tid;             // 0..1535
    const int row = c / 24, cl = c - row * 24;
    const int cg = cl ^ (row & 7);
    kld[i] = c * 8;
    if (cg < 16) { koff[i] = 262144 + (b * 2048 + row) * 4096 + h * 256 + cg * 8;
                   kstep[i] = 64 * 4096; }
    else         { koff[i] = (b * 2048 + row) * 64 + (cg - 16) * 8;
                   kstep[i] = 64 * 64; }
  }
  int voff[4], vld[4];
#pragma unroll
  for (int i = 0; i < 4; ++i) {
    const int c = i * 256 + tid;             // 0..1023
    const int v = c >> 3, cl = c & 7;
    const int cg = cl ^ (v & 7);
    vld[i] = c * 8;
    voff[i] = (bh * 128 + v) * 2048 + cg * 8;
  }

  bf16x8 qf[2][6];
#pragma unroll
  for (int m = 0; m < 2; ++m)
#pragma unroll
    for (int kd = 0; kd < 6; ++kd)
      qf[m][kd] = *(const bf16x8*)(q + (size_t)(b * 2048 + qrb + m * 16 + lr) * 3072 +
                                   h * 192 + kd * 32 + g * 8);

  float mrow[2][4], lrow[2][4];
  f32x4 o[2][8] = {};
#pragma unroll
  for (int m = 0; m < 2; ++m)
#pragma unroll
    for (int i = 0; i < 4; ++i) { mrow[m][i] = -1e30f; lrow[m][i] = 0.f; }

  const int nt = (q0 >> 6) + 2;
  for (int t = 0; t < nt; ++t) {
    const int k0 = t * 64;
#pragma unroll
    for (int i = 0; i < 6; ++i) {
      GLOAD16(kpe + koff[i], &Ks[kld[i]]);
      koff[i] += kstep[i];
    }
#pragma unroll
    for (int i = 0; i < 4; ++i) {
      GLOAD16(vT + voff[i], &Vt[vld[i]]);
      voff[i] += 64;
    }
    __syncthreads();                         // publishes Ks/Vt for this tile

    const bool active = (k0 <= qrb + 31);    // wave-uniform
    if (active) {
      f32x4 sAcc[2][4] = {};
      __builtin_amdgcn_s_setprio(1);
#pragma unroll
      for (int nf = 0; nf < 4; ++nf) {
        const int rr = nf * 16 + lr;
#pragma unroll
        for (int kd = 0; kd < 6; ++kd) {
          const int ch = (kd * 4 + g) ^ (rr & 7);
          const bf16x8 kf = *(const bf16x8*)(&Ks[rr * 192 + ch * 8]);
#pragma unroll
          for (int m = 0; m < 2; ++m)
            sAcc[m][nf] = __builtin_amdgcn_mfma_f32_16x16x32_bf16(qf[m][kd], kf, sAcc[m][nf], 0, 0, 0);
        }
      }
      __builtin_amdgcn_s_setprio(0);

      const bool needMask = (k0 + 63 > qrb); // wave-uniform: diagonal tiles only
#pragma unroll
      for (int m = 0; m < 2; ++m) {
        float sv[4][4];
        if (needMask) {
#pragma unroll
          for (int nf = 0; nf < 4; ++nf)
#pragma unroll
            for (int i = 0; i < 4; ++i) {
              const int qrow = qrb + m * 16 + g * 4 + i;
              const int kcol = k0 + nf * 16 + lr;
              sv[nf][i] = (kcol > qrow) ? -1e30f : sAcc[m][nf][i];
            }
        } else {
#pragma unroll
          for (int nf = 0; nf < 4; ++nf)
#pragma unroll
            for (int i = 0; i < 4; ++i) sv[nf][i] = sAcc[m][nf][i];
        }
        float rm4[4];
        bool exceed = false;
#pragma unroll
        for (int i = 0; i < 4; ++i) {
          float rm = fmaxf(fmaxf(sv[0][i], sv[1][i]), fmaxf(sv[2][i], sv[3][i]));
          rm = fmaxf(rm, __shfl_xor(rm, 1));
          rm = fmaxf(rm, __shfl_xor(rm, 2));
          rm = fmaxf(rm, __shfl_xor(rm, 4));
          rm = fmaxf(rm, __shfl_xor(rm, 8));
          rm4[i] = rm;
          exceed = exceed || (rm > mrow[m][i] + 8.0f);
        }
        if (__any(exceed)) {                 // T13: rescale only on real max growth
#pragma unroll
          for (int i = 0; i < 4; ++i) {
            const float mn = fmaxf(mrow[m][i], rm4[i]);
            const float fac = __expf(mrow[m][i] - mn);
            mrow[m][i] = mn;
            lrow[m][i] *= fac;
#pragma unroll
            for (int nv = 0; nv < 8; ++nv) o[m][nv][i] *= fac;
          }
        }
#pragma unroll
        for (int i = 0; i < 4; ++i) {
          float rsum = 0.f;
#pragma unroll
          for (int nf = 0; nf < 4; ++nf) { sv[nf][i] = __expf(sv[nf][i] - mrow[m][i]); rsum += sv[nf][i]; }
          rsum += __shfl_xor(rsum, 1);
          rsum += __shfl_xor(rsum, 2);
          rsum += __shfl_xor(rsum, 4);
          rsum += __shfl_xor(rsum, 8);
          lrow[m][i] += rsum;
        }
#pragma unroll
        for (int nf = 0; nf < 4; ++nf)
#pragma unroll
          for (int i = 0; i < 4; ++i)
            Psw[(m * 16 + g * 4 + i) * 72 + nf * 16 + lr] = f2bf(sv[nf][i]);
      }
      asm volatile("s_waitcnt lgkmcnt(0)" ::: "memory");

      __builtin_amdgcn_s_setprio(1);
#pragma unroll
      for (int kc = 0; kc < 2; ++kc) {
        bf16x8 vfr[8];
#pragma unroll
        for (int nv = 0; nv < 8; ++nv) {
          const int v = nv * 16 + lr;
          const int cx = (kc * 4 + g) ^ (v & 7);
          vfr[nv] = *(const bf16x8*)(&Vt[v * 64 + cx * 8]);
        }
#pragma unroll
        for (int m = 0; m < 2; ++m) {
          const bf16x8 pf = *(const bf16x8*)(&Psw[(m * 16 + lr) * 72 + kc * 32 + g * 8]);
#pragma unroll
          for (int nv = 0; nv < 8; ++nv)
            o[m][nv] = __builtin_amdgcn_mfma_f32_16x16x32_bf16(pf, vfr[nv], o[m][nv], 0, 0, 0);
        }
      }
      __builtin_amdgcn_s_setprio(0);
    }
    __syncthreads();                         // Ks/Vt/Ps reads done before next stage
  }

#pragma unroll
  for (int m = 0; m < 2; ++m)
#pragma unroll
    for (int i = 0; i < 4; ++i) {
      const float inv = 1.0f / lrow[m][i];
      const size_t tokOff = (size_t)(b * 2048 + qrb + m * 16 + g * 4 + i) * 2048 + h * 128;
#pragma unroll
      for (int nv = 0; nv < 8; ++nv)
        ao[tokOff + nv * 16 + lr] = f2bf(o[m][nv][i] * inv);
    }
}

// -----------------------------------------------------------------------------
extern "C" void kernel_launch(void* const* d_in, const int* in_sizes, int n_in,
                              void* d_out, int out_size, void* d_ws, size_t ws_size,
                              hipStream_t stream) {
  const float* hidden  = (const float*)d_in[0];
  const int*   pos     = (const int*)d_in[1];
  const float* q_a_w   = (const float*)d_in[2];
  const float* q_a_ln  = (const float*)d_in[3];
  const float* q_b_w   = (const float*)d_in[4];
  const float* kv_a_w  = (const float*)d_in[5];
  const float* kv_a_ln = (const float*)d_in[6];
  const float* kv_b_w  = (const float*)d_in[7];
  const float* o_w     = (const float*)d_in[8];
  float* out = (float*)d_out;

  char* ws = (char*)d_ws;
  u16* hb  = (u16*)(ws + 0L);          // 4096x2048; reused as vT after fused a-GEMM
  u16* wA  = (u16*)(ws + 16777216L);   // 2176x2048 (q_a_w rows 0..1535, kv_a_w rows 1536..2111, pad to 2176)
  u16* w2  = (u16*)(ws + 25690112L);   // 3072x1536
  u16* w4  = (u16*)(ws + 35127296L);   // 4096x512
  u16* w5  = (u16*)(ws + 39321600L);   // 2048x2048
  u16* qa  = (u16*)(ws + 47710208L);   // 4096x1536
  u16* qb  = (u16*)(ws + 60293120L);   // 4096x3072
  u16* ckv = (u16*)(ws + 85458944L);   // 4096x512
  u16* kpe = (u16*)(ws + 89653248L);   // 4096x64   (kvb = kpe + 262144 elements!)
  u16* kvb = (u16*)(ws + 90177536L);   // 4096x4096 (qk_a tmp aliases this region)
  u16* ao  = (u16*)(ws + 123731968L);  // 4096x2048 -> ends 140509184
  u16* qk_a = kvb;                     // 4096x2176 fused a-GEMM output (dead before kvb written)
  u16* vT  = hb;                       // 4096x2048
  if (ws_size < 145752064UL) { fprintf(stderr, "ws too small: %zu\n", ws_size); return; }

  const float SCALE = 0.07216878364870323f;  // 192^-0.5, folded into q_b GEMM

  auto cvt = [&](const float* s, u16* d, long sn, long dn) {
    long blocks = (dn / 8 + 255) / 256; if (blocks > 2048) blocks = 2048;
    cvt_pad_k<<<dim3((unsigned)blocks), dim3(256), 0, stream>>>(s, d, sn, dn);
  };
  cvt(hidden, hb, 4096L * 2048, 4096L * 2048);
  cvt(q_a_w,  wA, 1536L * 2048, 1536L * 2048);
  cvt(kv_a_w, wA + 1536L * 2048, 576L * 2048, 640L * 2048);
  cvt(q_b_w,  w2, 3072L * 1536, 3072L * 1536);
  cvt(kv_b_w, w4, 4096L * 512,  4096L * 512);
  cvt(o_w,    w5, 2048L * 2048, 2048L * 2048);

  // fused q_a + kv_a projection: qk_a[4096][2176]
  gemm_bt<<<dim3(17, 32), 256, 0, stream>>>(hb, wA, qk_a, nullptr, 4096, 2176, 2048, 1.0f);
  rms_k<<<4096, 256, 0, stream>>>(qk_a, qa, q_a_ln, 2176, 1536, 1536);
  rms_k<<<4096, 256, 0, stream>>>(qk_a + 1536, ckv, kv_a_ln, 2176, 512, 512);
  gemm256<<<dim3(12, 16), 512, 0, stream>>>(qa, w2, qb, nullptr, 4096, 3072, 1536, SCALE);
  rope_k<<<4096, 256, 0, stream>>>(qb, qk_a, kpe, pos);   // reads qk_a: before kvb overwrite
  gemm256<<<dim3(16, 16), 512, 0, stream>>>(ckv, w4, kvb, nullptr, 4096, 4096, 512, 1.0f);
  vtr_k<<<dim3(32, 32), 256, 0, stream>>>(kvb, vT);
  attn_k<<<dim3(32, 16), 256, 0, stream>>>(qb, kpe, vT, ao);
  gemm256<<<dim3(8, 16), 512, 0, stream>>>(ao, w5, nullptr, out, 4096, 2048, 2048, 1.0f);
}

// Round 18
// 423.267 us; speedup vs baseline: 1.2033x; 1.0227x over previous
//
#include <hip/hip_runtime.h>
#include <cstdio>

typedef unsigned short u16;
typedef u16 u16x4 __attribute__((ext_vector_type(4)));
typedef u16 u16x8 __attribute__((ext_vector_type(8)));
typedef __bf16 bf16x8 __attribute__((ext_vector_type(8)));
typedef float f32x4 __attribute__((ext_vector_type(4)));

#define AS1 __attribute__((address_space(1)))
#define AS3 __attribute__((address_space(3)))

#define GLOAD16(gsrc, ldst) __builtin_amdgcn_global_load_lds( \
    (const AS1 void*)(gsrc), (AS3 void*)(ldst), 16, 0, 0)

__device__ __forceinline__ u16 f2bf(float f) {
  unsigned u = __builtin_bit_cast(unsigned, f);
  u += 0x7fffu + ((u >> 16) & 1u);
  return (u16)(u >> 16);
}
__device__ __forceinline__ float bf2f(u16 h) {
  return __builtin_bit_cast(float, (unsigned)h << 16);
}

// ---------------- fp32 -> bf16 convert (with trailing-row zero pad) ----------
__global__ __launch_bounds__(256) void cvt_pad_k(const float* __restrict__ src,
                                                 u16* __restrict__ dst,
                                                 long srcN, long dstN) {
  long i = ((long)blockIdx.x * 256 + threadIdx.x) * 8;
  const long stride = (long)gridDim.x * 256 * 8;
  for (; i < dstN; i += stride) {
    u16x8 o = {0,0,0,0,0,0,0,0};
    if (i < srcN) {
      const float4* p = (const float4*)(src + i);
      float4 a = p[0], b = p[1];
      o[0]=f2bf(a.x); o[1]=f2bf(a.y); o[2]=f2bf(a.z); o[3]=f2bf(a.w);
      o[4]=f2bf(b.x); o[5]=f2bf(b.y); o[6]=f2bf(b.z); o[7]=f2bf(b.w);
    }
    *(u16x8*)(dst + i) = o;
  }
}

// ---------------- RMSNorm over last dim (bf16 in/out, fp32 math) -------------
__global__ __launch_bounds__(256) void rms_k(const u16* __restrict__ src, u16* __restrict__ dst,
                                             const float* __restrict__ w,
                                             int sstride, int dstride, int cols) {
  const int row = blockIdx.x;
  const int tid = threadIdx.x;
  const int nch = cols >> 3;
  float x[8];
  float ss = 0.f;
  if (tid < nch) {
    u16x8 v = *(const u16x8*)(src + (size_t)row * sstride + tid * 8);
#pragma unroll
    for (int j = 0; j < 8; ++j) { x[j] = bf2f(v[j]); ss += x[j] * x[j]; }
  } else {
#pragma unroll
    for (int j = 0; j < 8; ++j) x[j] = 0.f;
  }
#pragma unroll
  for (int off = 1; off < 64; off <<= 1) ss += __shfl_xor(ss, off);
  __shared__ float red[4];
  const int wv = tid >> 6, ln = tid & 63;
  if (ln == 0) red[wv] = ss;
  __syncthreads();
  const float tot = red[0] + red[1] + red[2] + red[3];
  const float rs = 1.0f / sqrtf(tot / (float)cols + 1e-6f);
  if (tid < nch) {
    u16x8 o;
#pragma unroll
    for (int j = 0; j < 8; ++j) o[j] = f2bf(x[j] * rs * w[tid * 8 + j]);
    *(u16x8*)(dst + (size_t)row * dstride + tid * 8) = o;
  }
}

// ---------------- RoPE: q_pe (in place, 16 heads) + k_pe -> kpe --------------
__global__ __launch_bounds__(256) void rope_k(u16* __restrict__ q, const u16* __restrict__ qk_a,
                                              u16* __restrict__ kpe, const int* __restrict__ pos) {
  const int tok = blockIdx.x;          // 0..4095
  const int j = threadIdx.x & 63;
  const int w = threadIdx.x >> 6;
  const float p = (float)pos[tok];
  const int jj = j & 31;
  const float inv = __powf(10000.0f, -(float)jj * (1.0f / 32.0f));
  float s, c;
  __sincosf(p * inv, &s, &c);
  const float sgn = (j < 32) ? -1.0f : 1.0f;
  const int partner = (j < 32) ? j + 32 : j - 32;
  if (w == 0) {
    const float x  = bf2f(qk_a[(size_t)tok * 2176 + 2048 + j]);
    const float xp = bf2f(qk_a[(size_t)tok * 2176 + 2048 + partner]);
    kpe[(size_t)tok * 64 + j] = f2bf(x * c + sgn * xp * s);
  }
#pragma unroll
  for (int hh = 0; hh < 4; ++hh) {
    const int h = w * 4 + hh;
    const size_t base = (size_t)tok * 3072 + h * 192 + 128;
    const float x  = bf2f(q[base + j]);
    const float xp = bf2f(q[base + partner]);
    q[base + j] = f2bf(x * c + sgn * xp * s);
  }
}

// ---------------- bf16 GEMM 128x128 (m97 structure) --------------------------
// cs: epilogue scale. vTr != nullptr => kv_b mode: within each head's 256-col
// block, cols 0..127 (k_nope) go to Cb normally; cols 128..255 (V) are written
// TRANSPOSED to vTr[bh*128+v][seq] as packed u16x4 (fuses the old vtr_k pass).
__global__ __launch_bounds__(256) void gemm_bt(const u16* __restrict__ A, const u16* __restrict__ B,
                                               u16* __restrict__ Cb, float* __restrict__ Cf,
                                               int M, int N, int K, float cs,
                                               u16* __restrict__ vTr) {
  __shared__ __attribute__((aligned(16))) u16 As[128 * 64];
  __shared__ __attribute__((aligned(16))) u16 Bs[128 * 64];
  const int tid = threadIdx.x;
  const int m0 = blockIdx.y * 128, n0 = blockIdx.x * 128;
  const int w = tid >> 6, lane = tid & 63;
  const int wr = w >> 1, wc = w & 1;
  const int lr = lane & 15, g = lane >> 4;

  f32x4 acc[4][4] = {};

  for (int k0 = 0; k0 < K; k0 += 64) {
#pragma unroll
    for (int i = 0; i < 4; ++i) {
      const int c = i * 256 + tid;
      const int row = c >> 3, col = (c & 7) << 3;
      GLOAD16(A + (size_t)(m0 + row) * K + k0 + col, &As[c * 8]);
    }
#pragma unroll
    for (int i = 0; i < 4; ++i) {
      const int c = i * 256 + tid;
      const int row = c >> 3, col = (c & 7) << 3;
      GLOAD16(B + (size_t)(n0 + row) * K + k0 + col, &Bs[c * 8]);
    }
    __syncthreads();
    bf16x8 af[4][2], bfr[4][2];
#pragma unroll
    for (int x = 0; x < 4; ++x)
#pragma unroll
      for (int kk = 0; kk < 2; ++kk) {
        af[x][kk]  = *(const bf16x8*)(&As[(wr * 64 + x * 16 + lr) * 64 + kk * 32 + g * 8]);
        bfr[x][kk] = *(const bf16x8*)(&Bs[(wc * 64 + x * 16 + lr) * 64 + kk * 32 + g * 8]);
      }
#pragma unroll
    for (int mi = 0; mi < 4; ++mi)
#pragma unroll
      for (int ni = 0; ni < 4; ++ni)
#pragma unroll
        for (int kk = 0; kk < 2; ++kk)
          acc[mi][ni] = __builtin_amdgcn_mfma_f32_16x16x32_bf16(af[mi][kk], bfr[ni][kk],
                                                                acc[mi][ni], 0, 0, 0);
    __syncthreads();
  }

  const int rb = m0 + wr * 64, cb = n0 + wc * 64;
#pragma unroll
  for (int mi = 0; mi < 4; ++mi)
#pragma unroll
    for (int ni = 0; ni < 4; ++ni) {
      const int r = rb + mi * 16 + g * 4;
      const int cI = cb + ni * 16 + lr;
      if (vTr) {
        const u16 v0 = f2bf(acc[mi][ni][0]), v1 = f2bf(acc[mi][ni][1]);
        const u16 v2 = f2bf(acc[mi][ni][2]), v3 = f2bf(acc[mi][ni][3]);
        if ((cI & 255) < 128) {               // k_nope -> kvb (row-major)
          Cb[(size_t)(r + 0) * N + cI] = v0;
          Cb[(size_t)(r + 1) * N + cI] = v1;
          Cb[(size_t)(r + 2) * N + cI] = v2;
          Cb[(size_t)(r + 3) * N + cI] = v3;
        } else {                              // V -> vT[bh*128+v][seq], packed
          u16x4 tq = {v0, v1, v2, v3};
          const int bh = ((r >> 11) << 4) + (cI >> 8);
          *(u16x4*)(vTr + (size_t)(bh * 128 + (cI & 127)) * 2048 + (r & 2047)) = tq;
        }
      } else {
#pragma unroll
        for (int i = 0; i < 4; ++i) {
          if (Cf) Cf[(size_t)(r + i) * N + cI] = acc[mi][ni][i] * cs;
          else    Cb[(size_t)(r + i) * N + cI] = f2bf(acc[mi][ni][i] * cs);
        }
      }
    }
}

// ---------------- causal flash attention, per (b,head) -----------------------
// r17 template unchanged: heavy-first grid (LPT backfill), KV tile 64, own Ps
// (2 barriers/tile), hoisted int32 staging offsets (kvb = kpe + 262144 elems),
// Q pre-scaled, defer-max, diagonal-only masking, setprio on MFMA clusters.
__global__ __launch_bounds__(256) void attn_k(const u16* __restrict__ q, const u16* __restrict__ kpe,
                                              const u16* __restrict__ vT, u16* __restrict__ ao) {
  __shared__ __attribute__((aligned(16))) u16 Ks[64 * 192];
  __shared__ __attribute__((aligned(16))) u16 Vt[128 * 64];
  __shared__ __attribute__((aligned(16))) u16 Ps[4][32 * 72];

  const int bh = blockIdx.x;
  const int b = bh >> 4, h = bh & 15;
  const int j = 15 - blockIdx.y;             // heavy q-tiles dispatch first (LPT)
  const int tid = threadIdx.x, w = tid >> 6, lane = tid & 63;
  const int lr = lane & 15, g = lane >> 4;

  const int q0 = j * 128;
  const int qrb = q0 + w * 32;
  u16* Psw = &Ps[w][0];

  int koff[6], kstep[6], kld[6];
#pragma unroll
  for (int i = 0; i < 6; ++i) {
    const int c = i * 256 + tid;             // 0..1535
    const int row = c / 24, cl = c - row * 24;
    const int cg = cl ^ (row & 7);
    kld[i] = c * 8;
    if (cg < 16) { koff[i] = 262144 + (b * 2048 + row) * 4096 + h * 256 + cg * 8;
                   kstep[i] = 64 * 4096; }
    else         { koff[i] = (b * 2048 + row) * 64 + (cg - 16) * 8;
                   kstep[i] = 64 * 64; }
  }
  int voff[4], vld[4];
#pragma unroll
  for (int i = 0; i < 4; ++i) {
    const int c = i * 256 + tid;             // 0..1023
    const int v = c >> 3, cl = c & 7;
    const int cg = cl ^ (v & 7);
    vld[i] = c * 8;
    voff[i] = (bh * 128 + v) * 2048 + cg * 8;
  }

  bf16x8 qf[2][6];
#pragma unroll
  for (int m = 0; m < 2; ++m)
#pragma unroll
    for (int kd = 0; kd < 6; ++kd)
      qf[m][kd] = *(const bf16x8*)(q + (size_t)(b * 2048 + qrb + m * 16 + lr) * 3072 +
                                   h * 192 + kd * 32 + g * 8);

  float mrow[2][4], lrow[2][4];
  f32x4 o[2][8] = {};
#pragma unroll
  for (int m = 0; m < 2; ++m)
#pragma unroll
    for (int i = 0; i < 4; ++i) { mrow[m][i] = -1e30f; lrow[m][i] = 0.f; }

  const int nt = (q0 >> 6) + 2;
  for (int t = 0; t < nt; ++t) {
    const int k0 = t * 64;
#pragma unroll
    for (int i = 0; i < 6; ++i) {
      GLOAD16(kpe + koff[i], &Ks[kld[i]]);
      koff[i] += kstep[i];
    }
#pragma unroll
    for (int i = 0; i < 4; ++i) {
      GLOAD16(vT + voff[i], &Vt[vld[i]]);
      voff[i] += 64;
    }
    __syncthreads();                         // publishes Ks/Vt for this tile

    const bool active = (k0 <= qrb + 31);    // wave-uniform
    if (active) {
      f32x4 sAcc[2][4] = {};
      __builtin_amdgcn_s_setprio(1);
#pragma unroll
      for (int nf = 0; nf < 4; ++nf) {
        const int rr = nf * 16 + lr;
#pragma unroll
        for (int kd = 0; kd < 6; ++kd) {
          const int ch = (kd * 4 + g) ^ (rr & 7);
          const bf16x8 kf = *(const bf16x8*)(&Ks[rr * 192 + ch * 8]);
#pragma unroll
          for (int m = 0; m < 2; ++m)
            sAcc[m][nf] = __builtin_amdgcn_mfma_f32_16x16x32_bf16(qf[m][kd], kf, sAcc[m][nf], 0, 0, 0);
        }
      }
      __builtin_amdgcn_s_setprio(0);

      const bool needMask = (k0 + 63 > qrb); // wave-uniform: diagonal tiles only
#pragma unroll
      for (int m = 0; m < 2; ++m) {
        float sv[4][4];
        if (needMask) {
#pragma unroll
          for (int nf = 0; nf < 4; ++nf)
#pragma unroll
            for (int i = 0; i < 4; ++i) {
              const int qrow = qrb + m * 16 + g * 4 + i;
              const int kcol = k0 + nf * 16 + lr;
              sv[nf][i] = (kcol > qrow) ? -1e30f : sAcc[m][nf][i];
            }
        } else {
#pragma unroll
          for (int nf = 0; nf < 4; ++nf)
#pragma unroll
            for (int i = 0; i < 4; ++i) sv[nf][i] = sAcc[m][nf][i];
        }
        float rm4[4];
        bool exceed = false;
#pragma unroll
        for (int i = 0; i < 4; ++i) {
          float rm = fmaxf(fmaxf(sv[0][i], sv[1][i]), fmaxf(sv[2][i], sv[3][i]));
          rm = fmaxf(rm, __shfl_xor(rm, 1));
          rm = fmaxf(rm, __shfl_xor(rm, 2));
          rm = fmaxf(rm, __shfl_xor(rm, 4));
          rm = fmaxf(rm, __shfl_xor(rm, 8));
          rm4[i] = rm;
          exceed = exceed || (rm > mrow[m][i] + 8.0f);
        }
        if (__any(exceed)) {                 // T13: rescale only on real max growth
#pragma unroll
          for (int i = 0; i < 4; ++i) {
            const float mn = fmaxf(mrow[m][i], rm4[i]);
            const float fac = __expf(mrow[m][i] - mn);
            mrow[m][i] = mn;
            lrow[m][i] *= fac;
#pragma unroll
            for (int nv = 0; nv < 8; ++nv) o[m][nv][i] *= fac;
          }
        }
#pragma unroll
        for (int i = 0; i < 4; ++i) {
          float rsum = 0.f;
#pragma unroll
          for (int nf = 0; nf < 4; ++nf) { sv[nf][i] = __expf(sv[nf][i] - mrow[m][i]); rsum += sv[nf][i]; }
          rsum += __shfl_xor(rsum, 1);
          rsum += __shfl_xor(rsum, 2);
          rsum += __shfl_xor(rsum, 4);
          rsum += __shfl_xor(rsum, 8);
          lrow[m][i] += rsum;
        }
#pragma unroll
        for (int nf = 0; nf < 4; ++nf)
#pragma unroll
          for (int i = 0; i < 4; ++i)
            Psw[(m * 16 + g * 4 + i) * 72 + nf * 16 + lr] = f2bf(sv[nf][i]);
      }
      asm volatile("s_waitcnt lgkmcnt(0)" ::: "memory");

      __builtin_amdgcn_s_setprio(1);
#pragma unroll
      for (int kc = 0; kc < 2; ++kc) {
        bf16x8 vfr[8];
#pragma unroll
        for (int nv = 0; nv < 8; ++nv) {
          const int v = nv * 16 + lr;
          const int cx = (kc * 4 + g) ^ (v & 7);
          vfr[nv] = *(const bf16x8*)(&Vt[v * 64 + cx * 8]);
        }
#pragma unroll
        for (int m = 0; m < 2; ++m) {
          const bf16x8 pf = *(const bf16x8*)(&Psw[(m * 16 + lr) * 72 + kc * 32 + g * 8]);
#pragma unroll
          for (int nv = 0; nv < 8; ++nv)
            o[m][nv] = __builtin_amdgcn_mfma_f32_16x16x32_bf16(pf, vfr[nv], o[m][nv], 0, 0, 0);
        }
      }
      __builtin_amdgcn_s_setprio(0);
    }
    __syncthreads();                         // Ks/Vt/Ps reads done before next stage
  }

#pragma unroll
  for (int m = 0; m < 2; ++m)
#pragma unroll
    for (int i = 0; i < 4; ++i) {
      const float inv = 1.0f / lrow[m][i];
      const size_t tokOff = (size_t)(b * 2048 + qrb + m * 16 + g * 4 + i) * 2048 + h * 128;
#pragma unroll
      for (int nv = 0; nv < 8; ++nv)
        ao[tokOff + nv * 16 + lr] = f2bf(o[m][nv][i] * inv);
    }
}

// -----------------------------------------------------------------------------
extern "C" void kernel_launch(void* const* d_in, const int* in_sizes, int n_in,
                              void* d_out, int out_size, void* d_ws, size_t ws_size,
                              hipStream_t stream) {
  const float* hidden  = (const float*)d_in[0];
  const int*   pos     = (const int*)d_in[1];
  const float* q_a_w   = (const float*)d_in[2];
  const float* q_a_ln  = (const float*)d_in[3];
  const float* q_b_w   = (const float*)d_in[4];
  const float* kv_a_w  = (const float*)d_in[5];
  const float* kv_a_ln = (const float*)d_in[6];
  const float* kv_b_w  = (const float*)d_in[7];
  const float* o_w     = (const float*)d_in[8];
  float* out = (float*)d_out;

  char* ws = (char*)d_ws;
  u16* hb  = (u16*)(ws + 0L);          // 4096x2048; reused as vT after fused a-GEMM
  u16* wA  = (u16*)(ws + 16777216L);   // 2176x2048 (q_a_w rows 0..1535, kv_a_w rows 1536..2111, pad)
  u16* w2  = (u16*)(ws + 25690112L);   // 3072x1536
  u16* w4  = (u16*)(ws + 35127296L);   // 4096x512
  u16* w5  = (u16*)(ws + 39321600L);   // 2048x2048
  u16* qa  = (u16*)(ws + 47710208L);   // 4096x1536
  u16* qb  = (u16*)(ws + 60293120L);   // 4096x3072
  u16* ckv = (u16*)(ws + 85458944L);   // 4096x512
  u16* kpe = (u16*)(ws + 89653248L);   // 4096x64   (kvb = kpe + 262144 elements!)
  u16* kvb = (u16*)(ws + 90177536L);   // 4096x4096 (qk_a tmp aliases this region)
  u16* ao  = (u16*)(ws + 123731968L);  // 4096x2048 -> ends 140509184
  u16* qk_a = kvb;                     // 4096x2176 fused a-GEMM output (dead before kvb written)
  u16* vT  = hb;                       // 4096x2048
  if (ws_size < 145752064UL) { fprintf(stderr, "ws too small: %zu\n", ws_size); return; }

  const float SCALE = 0.07216878364870323f;  // 192^-0.5, folded into q_b GEMM

  auto cvt = [&](const float* s, u16* d, long sn, long dn) {
    long blocks = (dn / 8 + 255) / 256; if (blocks > 2048) blocks = 2048;
    cvt_pad_k<<<dim3((unsigned)blocks), dim3(256), 0, stream>>>(s, d, sn, dn);
  };
  cvt(hidden, hb, 4096L * 2048, 4096L * 2048);
  cvt(q_a_w,  wA, 1536L * 2048, 1536L * 2048);
  cvt(kv_a_w, wA + 1536L * 2048, 576L * 2048, 640L * 2048);
  cvt(q_b_w,  w2, 3072L * 1536, 3072L * 1536);
  cvt(kv_b_w, w4, 4096L * 512,  4096L * 512);
  cvt(o_w,    w5, 2048L * 2048, 2048L * 2048);

  // fused q_a + kv_a projection: qk_a[4096][2176]
  gemm_bt<<<dim3(17, 32), 256, 0, stream>>>(hb, wA, qk_a, nullptr, 4096, 2176, 2048, 1.0f, nullptr);
  rms_k<<<4096, 256, 0, stream>>>(qk_a, qa, q_a_ln, 2176, 1536, 1536);
  rms_k<<<4096, 256, 0, stream>>>(qk_a + 1536, ckv, kv_a_ln, 2176, 512, 512);
  gemm_bt<<<dim3(24, 32), 256, 0, stream>>>(qa, w2, qb, nullptr, 4096, 3072, 1536, SCALE, nullptr);
  rope_k<<<4096, 256, 0, stream>>>(qb, qk_a, kpe, pos);   // reads qk_a: before kvb overwrite
  // kv_b projection with fused V-transpose (k_nope -> kvb, V -> vT)
  gemm_bt<<<dim3(32, 32), 256, 0, stream>>>(ckv, w4, kvb, nullptr, 4096, 4096, 512, 1.0f, vT);
  attn_k<<<dim3(32, 16), 256, 0, stream>>>(qb, kpe, vT, ao);
  gemm_bt<<<dim3(16, 32), 256, 0, stream>>>(ao, w5, nullptr, out, 4096, 2048, 2048, 1.0f, nullptr);
}